// Round 5
// baseline (904.712 us; speedup 1.0000x reference)
//
#include <hip/hip_runtime.h>
#include <hip/hip_bf16.h>

#define BATCH 400
#define NPATCH 196
#define DIM 384
#define RTRI 73920          // 384*385/2
#define NSUP 200
#define OUT_SCORE 0
#define OUT_ADC 125
#define OUT_CLS (125 + BATCH * RTRI)

// ws offsets in floats (total 602240 floats = 2.41 MB)
#define WS_W      0         // 400*196
#define WS_SQ     78400     // 400*384
#define WS_RSUM   232000    // 400*384 (atomic; zeroed each launch)
#define WS_RM     385600    // 400*384
#define WS_GM     539200    // 400
#define WS_QPART  539600    // 400*8
#define WS_DOTS   542800    // 200*200 (atomic; zeroed each launch)
#define WS_AD     582800    // 200*40
#define WS_QN     590800    // 200
#define WS_PN     591000    // 40
#define WS_PROTO  591040    // 25*384
#define WS_TSM    600640    // 25*64
#define WS_TOTAL  602240

typedef __attribute__((ext_vector_type(8))) short bf16x8;
typedef __attribute__((ext_vector_type(4))) short short4v;
typedef __attribute__((ext_vector_type(4))) float f32x4;

__device__ __forceinline__ float wave_reduce(float v) {
    #pragma unroll
    for (int o = 32; o; o >>= 1) v += __shfl_down(v, o);
    return v;
}

__device__ __forceinline__ unsigned short f2bf(float f) {
    unsigned int x = __float_as_uint(f);
    x += 0x7FFFu + ((x >> 16) & 1u);    // RNE
    return (unsigned short)(x >> 16);
}

__global__ void k_zero(float* __restrict__ p, int n) {
    int i = blockIdx.x * 256 + threadIdx.x;
    if (i < n) p[i] = 0.f;
}

// k1: cosine weights w, cls fp32 copy, sq[d] = diag of scaled Gram
__global__ __launch_bounds__(384) void k_prep(const float* __restrict__ lsn,
                                              float* __restrict__ ws,
                                              float* __restrict__ out) {
    int b = blockIdx.x, tid = threadIdx.x;
    __shared__ float clsL[DIM];
    __shared__ float wL[NPATCH];
    __shared__ float red[6];
    const float* base = lsn + (size_t)b * 197 * DIM;
    float c = base[tid];
    clsL[tid] = c;
    out[OUT_CLS + (size_t)b * DIM + tid] = c;
    float s = wave_reduce(c * c);
    int lane = tid & 63, wv = tid >> 6;
    if (!lane) red[wv] = s;
    __syncthreads();
    float clsn = fmaxf(sqrtf(red[0]+red[1]+red[2]+red[3]+red[4]+red[5]), 1e-8f);
    const float* patch = base + DIM;
    for (int p = wv; p < NPATCH; p += 6) {
        const float* pr = patch + p * DIM;
        float dot = 0.f, nsq = 0.f;
        #pragma unroll
        for (int t = 0; t < 6; t++) {
            float v = pr[lane + 64 * t];
            float cl = clsL[lane + 64 * t];
            dot = fmaf(v, cl, dot);
            nsq = fmaf(v, v, nsq);
        }
        dot = wave_reduce(dot);
        nsq = wave_reduce(nsq);
        if (!lane) {
            float val = dot / (clsn * fmaxf(sqrtf(nsq), 1e-8f));
            wL[p] = val;
            ws[WS_W + b * NPATCH + p] = val;
        }
    }
    __syncthreads();
    float acc = 0.f;
    for (int m = 0; m < NPATCH; m++) {
        float v = wL[m] * patch[m * DIM + tid];
        acc = fmaf(v, v, acc);
    }
    ws[WS_SQ + b * DIM + tid] = acc * (1.0f / 392.0f);
}

// k2: MFMA bf16 Gram, 128x128 triu blocks, pow epilogue + triu write + row sums
#define LDP 72              // LDS stride in bf16 halves (144B: 16B-aligned, uniform banks)
__global__ __launch_bounds__(256) void k_gram(const float* __restrict__ lsn,
                                              float* __restrict__ ws,
                                              float* __restrict__ out) {
    int b = blockIdx.y;
    int t = blockIdx.x;                 // 0..5 -> triu (ti,tj) of 3x3
    int ti = (t < 3) ? 0 : ((t < 5) ? 1 : 2);
    int tj = (t < 3) ? t : ((t < 5) ? t - 2 : 2);

    __shared__ unsigned short pA[128 * LDP];
    __shared__ unsigned short pB[128 * LDP];

    int tid = threadIdx.x;
    int lane = tid & 63, w = tid >> 6;
    int wr = w >> 1, wc = w & 1;        // 2x2 waves, each 64x64

    const float* patch = lsn + (size_t)b * 197 * DIM + DIM;
    const float* wrow = ws + WS_W + b * NPATCH;

    int sd = tid & 127;                 // staging d (0..127)
    int mh = tid >> 7;                  // staging m-half (0/1)
    int giA = ti * 128 + sd;
    int giB = tj * 128 + sd;

    f32x4 acc[4][4] = {};

    for (int c = 0; c < 4; ++c) {
        int m0 = c * 64;
        int msz = (c < 3) ? 64 : 32;    // padded chunk size
        if (mh * 32 < msz) {
            #pragma unroll
            for (int i = 0; i < 8; ++i) {
                int ml = mh * 32 + i * 4;
                int mg = m0 + ml;
                short4v va, vb;
                #pragma unroll
                for (int u = 0; u < 4; ++u) {
                    float wm = (mg + u < NPATCH) ? wrow[mg + u] : 0.f;
                    float a = (mg + u < NPATCH) ? wm * patch[(size_t)(mg + u) * DIM + giA] : 0.f;
                    float bv = (mg + u < NPATCH) ? wm * patch[(size_t)(mg + u) * DIM + giB] : 0.f;
                    va[u] = (short)f2bf(a);
                    vb[u] = (short)f2bf(bv);
                }
                *(short4v*)&pA[sd * LDP + ml] = va;
                *(short4v*)&pB[sd * LDP + ml] = vb;
            }
        }
        __syncthreads();
        int nks = msz >> 5;
        for (int ks = 0; ks < nks; ++ks) {
            int kb = ks * 32 + (lane >> 4) * 8;
            bf16x8 af[4], bf[4];
            #pragma unroll
            for (int tr = 0; tr < 4; ++tr)
                af[tr] = *(const bf16x8*)&pA[(wr * 64 + tr * 16 + (lane & 15)) * LDP + kb];
            #pragma unroll
            for (int tc = 0; tc < 4; ++tc)
                bf[tc] = *(const bf16x8*)&pB[(wc * 64 + tc * 16 + (lane & 15)) * LDP + kb];
            #pragma unroll
            for (int tr = 0; tr < 4; ++tr)
                #pragma unroll
                for (int tc = 0; tc < 4; ++tc)
                    acc[tr][tc] = __builtin_amdgcn_mfma_f32_16x16x32_bf16(
                        af[tr], bf[tc], acc[tr][tc], 0, 0, 0);
        }
        __syncthreads();
    }

    // epilogue
    const float* sqb = ws + WS_SQ + b * DIM;
    float sqi[4][4], sqj[4];
    int rbase = ti * 128 + wr * 64;
    int cbase = tj * 128 + wc * 64;
    #pragma unroll
    for (int tr = 0; tr < 4; ++tr)
        #pragma unroll
        for (int rg = 0; rg < 4; ++rg)
            sqi[tr][rg] = sqb[rbase + tr * 16 + (lane >> 4) * 4 + rg];
    #pragma unroll
    for (int tc = 0; tc < 4; ++tc)
        sqj[tc] = sqb[cbase + tc * 16 + (lane & 15)];

    float* adc = out + OUT_ADC + (size_t)b * RTRI;
    float rs[4][4] = {};
    float cs[4] = {0.f, 0.f, 0.f, 0.f};
    #pragma unroll
    for (int tr = 0; tr < 4; ++tr) {
        #pragma unroll
        for (int tc = 0; tc < 4; ++tc) {
            #pragma unroll
            for (int rg = 0; rg < 4; ++rg) {
                int gi = rbase + tr * 16 + (lane >> 4) * 4 + rg;
                int gj = cbase + tc * 16 + (lane & 15);
                float dc = sqi[tr][rg] + sqj[tc] - acc[tr][tc][rg] * (1.0f / 196.0f);
                if (gi == gj) dc = 0.f;
                dc = fmaxf(dc, 0.f) + 1e-5f;
                float val = __expf(0.4f * __logf(dc));
                rs[tr][rg] += val;
                cs[tc] += val;
                if (gj >= gi)
                    adc[gi * (769 - gi) / 2 + (gj - gi)] = val;
            }
        }
    }
    // row sums: butterfly over lanes sharing (lane>>4)
    #pragma unroll
    for (int tr = 0; tr < 4; ++tr)
        #pragma unroll
        for (int rg = 0; rg < 4; ++rg) {
            float v = rs[tr][rg];
            v += __shfl_xor(v, 1); v += __shfl_xor(v, 2);
            v += __shfl_xor(v, 4); v += __shfl_xor(v, 8);
            rs[tr][rg] = v;
        }
    if ((lane & 15) == 0) {
        #pragma unroll
        for (int tr = 0; tr < 4; ++tr)
            #pragma unroll
            for (int rg = 0; rg < 4; ++rg)
                atomicAdd(&ws[WS_RSUM + b * DIM + rbase + tr * 16 + (lane >> 4) * 4 + rg],
                          rs[tr][rg]);
    }
    // col sums credited to rows in tj-range (symmetry), off-diag blocks only
    if (ti != tj) {
        #pragma unroll
        for (int tc = 0; tc < 4; ++tc) {
            float v = cs[tc];
            v += __shfl_xor(v, 16); v += __shfl_xor(v, 32);
            cs[tc] = v;
        }
        if (lane < 16) {
            #pragma unroll
            for (int tc = 0; tc < 4; ++tc)
                atomicAdd(&ws[WS_RSUM + b * DIM + cbase + tc * 16 + lane], cs[tc]);
        }
    }
}

// k3: row means + grand mean
__global__ __launch_bounds__(384) void k_rowmean(float* __restrict__ ws) {
    int b = blockIdx.x, i = threadIdx.x;
    float s = ws[WS_RSUM + b * DIM + i];
    ws[WS_RM + b * DIM + i] = s * (1.0f / 384.0f);
    __shared__ float red[6];
    float tsum = wave_reduce(s);
    int lane = i & 63, wv = i >> 6;
    if (!lane) red[wv] = tsum;
    __syncthreads();
    if (i == 0) {
        float tot = red[0]+red[1]+red[2]+red[3]+red[4]+red[5];
        ws[WS_GM + b] = tot * (1.0f / (384.0f * 384.0f));
    }
}

// k4: in-place centering of adc (fp32) + per-row qnorm^2 partials
__global__ __launch_bounds__(256) void k_center(float* __restrict__ ws,
                                                float* __restrict__ out) {
    int split = blockIdx.x, b = blockIdx.y, tid = threadIdx.x;
    const float* rm = ws + WS_RM + b * DIM;
    float gm = ws[WS_GM + b];
    float* adc = out + OUT_ADC + (size_t)b * RTRI;
    float acc = 0.f;
    for (int c = tid; c < 2310; c += 256) {
        int e = split * 9240 + c * 4;
        float disc = 591361.0f - 8.0f * (float)e;
        int i = (int)((769.0f - sqrtf(disc)) * 0.5f);
        if (i < 0) i = 0;
        if (i > 383) i = 383;
        while (i > 0 && e < i * (769 - i) / 2) --i;
        while (e >= (i + 1) * (768 - i) / 2) ++i;
        int j = i + (e - i * (769 - i) / 2);
        #pragma unroll
        for (int u = 0; u < 4; u++) {
            float v = adc[e + u];
            float nv = v - rm[i] - rm[j] + gm;
            adc[e + u] = nv;
            acc = fmaf(nv, nv, acc);
            if (j == 383) { ++i; j = i; } else ++j;
        }
    }
    __shared__ float red[4];
    float tsum = wave_reduce(acc);
    if (!(tid & 63)) red[tid >> 6] = tsum;
    __syncthreads();
    if (!tid) ws[WS_QPART + b * 8 + split] = red[0] + red[1] + red[2] + red[3];
}

// k5: DOTS[r][c] = dot(query row r, ctx row c). 40x40 tile, 1 wave, 5x5 microtile.
#define KCD 35
#define NSPL 96
#define KSL 770            // 73920 / 96
__global__ __launch_bounds__(64) void k_dots(const float* __restrict__ out,
                                             float* __restrict__ ws) {
    int rb = blockIdx.x;
    int cb = blockIdx.y;
    int ns = blockIdx.z;
    int tid = threadIdx.x;
    int tx = tid & 7, ty = tid >> 3;
    __shared__ float qsT[KCD][41];
    __shared__ float csT[KCD][41];
    const float* adc = out + OUT_ADC;
    int lo = ns * KSL;
    const float* qbase = adc + (size_t)(NSUP + rb * 40) * RTRI + lo;
    const float* cbase = adc + (size_t)(cb * 40) * RTRI + lo;
    float acc[5][5] = {};
    for (int k0 = 0; k0 < KSL; k0 += KCD) {
        for (int idx = tid; idx < 40 * KCD; idx += 64) {
            int r = idx / KCD, k = idx % KCD;
            qsT[k][r] = qbase[(size_t)r * RTRI + k0 + k];
            csT[k][r] = cbase[(size_t)r * RTRI + k0 + k];
        }
        __syncthreads();
        #pragma unroll 5
        for (int k = 0; k < KCD; k++) {
            float qa[5], ca[5];
            #pragma unroll
            for (int i = 0; i < 5; i++) qa[i] = qsT[k][ty * 5 + i];
            #pragma unroll
            for (int j = 0; j < 5; j++) ca[j] = csT[k][tx * 5 + j];
            #pragma unroll
            for (int i = 0; i < 5; i++)
                #pragma unroll
                for (int j = 0; j < 5; j++)
                    acc[i][j] = fmaf(qa[i], ca[j], acc[i][j]);
        }
        __syncthreads();
    }
    #pragma unroll
    for (int i = 0; i < 5; i++)
        #pragma unroll
        for (int j = 0; j < 5; j++)
            atomicAdd(&ws[WS_DOTS + (rb * 40 + ty * 5 + i) * 200 + cb * 40 + tx * 5 + j],
                      acc[i][j]);
}

// k5b: pn[c*8+f] = ||z_proto|| = sqrt(sum_{a,b} dot(ctx_a, ctx_b)) / 5
__global__ __launch_bounds__(256) void k_pn(const int* __restrict__ labels,
                                            const float* __restrict__ out,
                                            float* __restrict__ ws) {
    int o = blockIdx.x;      // c*8+f
    int c = o >> 3, f = o & 7;
    int tid = threadIdx.x;
    __shared__ int rows[5];
    if (tid == 0) {
        int cnt = 0;
        for (int s = 0; s < 25; s++)
            if (labels[s] == c && cnt < 5) rows[cnt++] = s * 8 + f;
    }
    __syncthreads();
    const float* adc = out + OUT_ADC;
    float acc[15] = {};
    for (int k = tid; k < RTRI; k += 256) {
        float v[5];
        #pragma unroll
        for (int a = 0; a < 5; a++) v[a] = adc[(size_t)rows[a] * RTRI + k];
        int idx = 0;
        #pragma unroll
        for (int a = 0; a < 5; a++)
            #pragma unroll
            for (int b2 = a; b2 < 5; b2++) {
                acc[idx] = fmaf(v[a], v[b2], acc[idx]);
                idx++;
            }
    }
    __shared__ float red[15];
    if (tid < 15) red[tid] = 0.f;
    __syncthreads();
    #pragma unroll
    for (int i = 0; i < 15; i++) {
        float t = wave_reduce(acc[i]);
        if (!(tid & 63)) atomicAdd(&red[i], t);
    }
    __syncthreads();
    if (tid == 0) {
        float tot = 0.f;
        int idx = 0;
        #pragma unroll
        for (int a = 0; a < 5; a++)
            #pragma unroll
            for (int b2 = a; b2 < 5; b2++) {
                tot += (a == b2) ? red[idx] : 2.f * red[idx];
                idx++;
            }
        ws[WS_PN + o] = fmaxf(sqrtf(fmaxf(tot, 0.f)) * 0.2f, 1e-8f);
    }
}

// k6: qn + ad from DOTS + QPART
__global__ __launch_bounds__(256) void k_post(const int* __restrict__ labels,
                                              float* __restrict__ ws) {
    __shared__ int mem[5][5];
    int tid = threadIdx.x;
    if (tid == 0) {
        int cnt[5] = {0,0,0,0,0};
        for (int s = 0; s < 25; s++) { int c = labels[s]; if (cnt[c] < 5) mem[c][cnt[c]++] = s; }
    }
    __syncthreads();
    for (int r = tid; r < 200; r += 256) {
        float ssum = 0.f;
        #pragma unroll
        for (int k = 0; k < 8; k++) ssum += ws[WS_QPART + (200 + r) * 8 + k];
        ws[WS_QN + r] = fmaxf(sqrtf(fmaxf(ssum, 0.f)), 1e-8f);
    }
    for (int idx = tid; idx < 8000; idx += 256) {
        int r = idx / 40, o = idx % 40;
        int c = o >> 3, f = o & 7;
        float s = 0.f;
        #pragma unroll
        for (int a = 0; a < 5; a++)
            s += ws[WS_DOTS + r * 200 + mem[c][a] * 8 + f];
        ws[WS_AD + idx] = s * 0.2f;
    }
}

// k7: proto[q] = mean_f(query cls) + mean_all(support cls)
__global__ __launch_bounds__(384) void k_proto(const float* __restrict__ lsn,
                                               float* __restrict__ ws) {
    int tid = threadIdx.x;
    float tsv = 0.f;
    for (int r = 0; r < 200; r++) tsv += lsn[(size_t)r * 197 * DIM + tid];
    tsv *= (1.0f / 200.0f);
    for (int q = 0; q < 25; q++) {
        float s = 0.f;
        #pragma unroll
        for (int f = 0; f < 8; f++) s += lsn[(size_t)(200 + q * 8 + f) * 197 * DIM + tid];
        ws[WS_PROTO + q * DIM + tid] = s * (1.0f / 8.0f) + tsv;
    }
}

// k8: tsm[q][g] = proto[q] . gen_weight[g]
__global__ __launch_bounds__(64) void k_tsm(const float* __restrict__ gw,
                                            float* __restrict__ ws) {
    int q = blockIdx.x, g = threadIdx.x;
    const float* pr = ws + WS_PROTO + q * DIM;
    const float* gr = gw + g * DIM;
    float s = 0.f;
    for (int d = 0; d < DIM; d++) s = fmaf(pr[d], gr[d], s);
    ws[WS_TSM + q * 64 + g] = s;
}

// k9: final score
__global__ __launch_bounds__(128) void k_score(const float* __restrict__ ws,
                                               float* __restrict__ out) {
    int t = threadIdx.x;
    if (t >= 125) return;
    int q = t / 5, wway = t % 5;
    float s = 0.f;
    for (int f = 0; f < 8; f++) {
        float qn = ws[WS_QN + q * 8 + f];
        for (int g = 0; g < 8; g++) {
            float ad = ws[WS_AD + (q * 8 + f) * 40 + wway * 8 + g];
            float pnv = ws[WS_PN + wway * 8 + g];
            s += (ad / (qn * pnv)) * ws[WS_TSM + q * 64 + f * 8 + g];
        }
    }
    out[OUT_SCORE + t] = s;
}

extern "C" void kernel_launch(void* const* d_in, const int* in_sizes, int n_in,
                              void* d_out, int out_size, void* d_ws, size_t ws_size,
                              hipStream_t stream) {
    const float* lsn = (const float*)d_in[0];
    const float* gw = (const float*)d_in[1];
    const int* labels = (const int*)d_in[2];
    float* ws = (float*)d_ws;
    float* out = (float*)d_out;

    {
        int n = (WS_AD - WS_RSUM);
        k_zero<<<dim3((n + 255) / 256), dim3(256), 0, stream>>>(ws + WS_RSUM, n);
    }
    k_prep<<<dim3(BATCH), dim3(384), 0, stream>>>(lsn, ws, out);
    k_gram<<<dim3(6, BATCH), dim3(256), 0, stream>>>(lsn, ws, out);
    k_rowmean<<<dim3(BATCH), dim3(384), 0, stream>>>(ws);
    k_center<<<dim3(8, BATCH), dim3(256), 0, stream>>>(ws, out);
    k_dots<<<dim3(5, 5, NSPL), dim3(64), 0, stream>>>(out, ws);
    k_pn<<<dim3(40), dim3(256), 0, stream>>>(labels, out, ws);
    k_post<<<1, dim3(256), 0, stream>>>(labels, ws);
    k_proto<<<1, dim3(384), 0, stream>>>(lsn, ws);
    k_tsm<<<dim3(25), dim3(64), 0, stream>>>(gw, ws);
    k_score<<<1, dim3(128), 0, stream>>>(ws, out);
}

// Round 6
// 750.385 us; speedup vs baseline: 1.2057x; 1.2057x over previous
//
#include <hip/hip_runtime.h>
#include <hip/hip_bf16.h>

#define BATCH 400
#define NPATCH 196
#define DIM 384
#define RTRI 73920          // 384*385/2
#define NSUP 200
#define OUT_SCORE 0
#define OUT_ADC 125
#define OUT_CLS (125 + BATCH * RTRI)

// ws offsets in floats (total 602240 floats = 2.41 MB)
#define WS_W      0         // 400*196
#define WS_SQ     78400     // 400*384
#define WS_RSUM   232000    // 400*384 (atomic; zeroed each launch)
#define WS_RM     385600    // 400*384
#define WS_GM     539200    // 400
#define WS_QPART  539600    // 400*8
#define WS_DOTS   542800    // 200*200 (atomic; zeroed each launch)
#define WS_AD     582800    // 200*40
#define WS_QN     590800    // 200
#define WS_PN     591000    // 40
#define WS_PROTO  591040    // 25*384
#define WS_TSM    600640    // 25*64
#define WS_TOTAL  602240

__device__ __forceinline__ float wave_reduce(float v) {
    #pragma unroll
    for (int o = 32; o; o >>= 1) v += __shfl_down(v, o);
    return v;
}

__global__ void k_zero(float* __restrict__ p, int n) {
    int i = blockIdx.x * 256 + threadIdx.x;
    if (i < n) p[i] = 0.f;
}

// k1: cosine weights w, cls fp32 copy, sq[d] = diag of scaled Gram
__global__ __launch_bounds__(384) void k_prep(const float* __restrict__ lsn,
                                              float* __restrict__ ws,
                                              float* __restrict__ out) {
    int b = blockIdx.x, tid = threadIdx.x;
    __shared__ float clsL[DIM];
    __shared__ float wL[NPATCH];
    __shared__ float red[6];
    const float* base = lsn + (size_t)b * 197 * DIM;
    float c = base[tid];
    clsL[tid] = c;
    out[OUT_CLS + (size_t)b * DIM + tid] = c;
    float s = wave_reduce(c * c);
    int lane = tid & 63, wv = tid >> 6;
    if (!lane) red[wv] = s;
    __syncthreads();
    float clsn = fmaxf(sqrtf(red[0]+red[1]+red[2]+red[3]+red[4]+red[5]), 1e-8f);
    const float* patch = base + DIM;
    for (int p = wv; p < NPATCH; p += 6) {
        const float* pr = patch + p * DIM;
        float dot = 0.f, nsq = 0.f;
        #pragma unroll
        for (int t = 0; t < 6; t++) {
            float v = pr[lane + 64 * t];
            float cl = clsL[lane + 64 * t];
            dot = fmaf(v, cl, dot);
            nsq = fmaf(v, v, nsq);
        }
        dot = wave_reduce(dot);
        nsq = wave_reduce(nsq);
        if (!lane) {
            float val = dot / (clsn * fmaxf(sqrtf(nsq), 1e-8f));
            wL[p] = val;
            ws[WS_W + b * NPATCH + p] = val;
        }
    }
    __syncthreads();
    float acc = 0.f;
    for (int m = 0; m < NPATCH; m++) {
        float v = wL[m] * patch[m * DIM + tid];
        acc = fmaf(v, v, acc);
    }
    ws[WS_SQ + b * DIM + tid] = acc * (1.0f / 392.0f);
}

// k2: fp32 Gram, 128x128 triu blocks, 8x8 microtile, pow epilogue + triu write + row sums
#define TKG 28
#define LDG 132             // fp32 LDS stride (128+4)
__global__ __launch_bounds__(256) void k_gram(const float* __restrict__ lsn,
                                              float* __restrict__ ws,
                                              float* __restrict__ out) {
    int b = blockIdx.y;
    int t = blockIdx.x;                 // 0..5 -> triu (ti,tj) of 3x3
    int ti = (t < 3) ? 0 : ((t < 5) ? 1 : 2);
    int tj = (t < 3) ? t : ((t < 5) ? t - 2 : 2);

    __shared__ float As[TKG * LDG];
    __shared__ float Bs[TKG * LDG];

    int tid = threadIdx.x;
    int tx = tid & 15, ty = tid >> 4;

    const float* patch = lsn + (size_t)b * 197 * DIM + DIM;
    const float* wrow = ws + WS_W + b * NPATCH;

    float acc[8][8] = {};
    for (int k0 = 0; k0 < NPATCH; k0 += TKG) {     // 7 steps of 28, exact
        for (int idx = tid; idx < TKG * 128; idx += 256) {
            int mi = idx >> 7, cc = idx & 127;
            float wm = wrow[k0 + mi];
            const float* prow = patch + (size_t)(k0 + mi) * DIM;
            As[mi * LDG + cc] = wm * prow[ti * 128 + cc];
            Bs[mi * LDG + cc] = wm * prow[tj * 128 + cc];
        }
        __syncthreads();
        #pragma unroll 2
        for (int k = 0; k < TKG; ++k) {
            float av[8], bv[8];
            *(float4*)&av[0] = *(const float4*)&As[k * LDG + ty * 8];
            *(float4*)&av[4] = *(const float4*)&As[k * LDG + ty * 8 + 4];
            *(float4*)&bv[0] = *(const float4*)&Bs[k * LDG + tx * 4];
            *(float4*)&bv[4] = *(const float4*)&Bs[k * LDG + 64 + tx * 4];
            #pragma unroll
            for (int i = 0; i < 8; i++)
                #pragma unroll
                for (int j = 0; j < 8; j++)
                    acc[i][j] = fmaf(av[i], bv[j], acc[i][j]);
        }
        __syncthreads();
    }

    // epilogue
    const float* sqb = ws + WS_SQ + b * DIM;
    int rb0 = ti * 128 + ty * 8;
    int cb0 = tj * 128;
    float sqi[8], sqj[8];
    #pragma unroll
    for (int i = 0; i < 8; i++) sqi[i] = sqb[rb0 + i];
    #pragma unroll
    for (int j = 0; j < 4; j++) {
        sqj[j]     = sqb[cb0 + tx * 4 + j];
        sqj[4 + j] = sqb[cb0 + 64 + tx * 4 + j];
    }

    float* adc = out + OUT_ADC + (size_t)b * RTRI;
    float rs[8] = {}, cs[8] = {};
    #pragma unroll
    for (int i = 0; i < 8; i++) {
        int gi = rb0 + i;
        #pragma unroll
        for (int j = 0; j < 8; j++) {
            int gj = cb0 + ((j < 4) ? (tx * 4 + j) : (64 + tx * 4 + (j - 4)));
            float dc = sqi[i] + sqj[j] - acc[i][j] * (1.0f / 196.0f);
            dc = fmaxf(dc, 0.f) + 1e-5f;
            float val = __expf(0.4f * __logf(dc));
            rs[i] += val;
            cs[j] += val;
            if (gj >= gi)
                adc[gi * (769 - gi) / 2 + (gj - gi)] = val;
        }
    }
    // row sums: butterfly over tx (lane bits 0..3); lanes sharing ty hold same rows
    #pragma unroll
    for (int i = 0; i < 8; i++) {
        float v = rs[i];
        v += __shfl_xor(v, 1); v += __shfl_xor(v, 2);
        v += __shfl_xor(v, 4); v += __shfl_xor(v, 8);
        rs[i] = v;
    }
    if ((tid & 15) == 0) {
        #pragma unroll
        for (int i = 0; i < 8; i++)
            atomicAdd(&ws[WS_RSUM + b * DIM + rb0 + i], rs[i]);
    }
    // col sums credited to rows in tj-range (symmetry), off-diag blocks only
    if (ti != tj) {
        #pragma unroll
        for (int j = 0; j < 8; j++) {
            float v = cs[j];
            v += __shfl_xor(v, 16); v += __shfl_xor(v, 32);
            cs[j] = v;
        }
        if ((tid & 63) < 16) {
            #pragma unroll
            for (int j = 0; j < 8; j++) {
                int gj = cb0 + ((j < 4) ? (tx * 4 + j) : (64 + tx * 4 + (j - 4)));
                atomicAdd(&ws[WS_RSUM + b * DIM + gj], cs[j]);
            }
        }
    }
}

// k3: row means + grand mean
__global__ __launch_bounds__(384) void k_rowmean(float* __restrict__ ws) {
    int b = blockIdx.x, i = threadIdx.x;
    float s = ws[WS_RSUM + b * DIM + i];
    ws[WS_RM + b * DIM + i] = s * (1.0f / 384.0f);
    __shared__ float red[6];
    float tsum = wave_reduce(s);
    int lane = i & 63, wv = i >> 6;
    if (!lane) red[wv] = tsum;
    __syncthreads();
    if (i == 0) {
        float tot = red[0]+red[1]+red[2]+red[3]+red[4]+red[5];
        ws[WS_GM + b] = tot * (1.0f / (384.0f * 384.0f));
    }
}

// k4: in-place centering of adc (fp32) + per-row qnorm^2 partials
__global__ __launch_bounds__(256) void k_center(float* __restrict__ ws,
                                                float* __restrict__ out) {
    int split = blockIdx.x, b = blockIdx.y, tid = threadIdx.x;
    const float* rm = ws + WS_RM + b * DIM;
    float gm = ws[WS_GM + b];
    float* adc = out + OUT_ADC + (size_t)b * RTRI;
    float acc = 0.f;
    for (int c = tid; c < 2310; c += 256) {
        int e = split * 9240 + c * 4;
        float disc = 591361.0f - 8.0f * (float)e;
        int i = (int)((769.0f - sqrtf(disc)) * 0.5f);
        if (i < 0) i = 0;
        if (i > 383) i = 383;
        while (i > 0 && e < i * (769 - i) / 2) --i;
        while (e >= (i + 1) * (768 - i) / 2) ++i;
        int j = i + (e - i * (769 - i) / 2);
        #pragma unroll
        for (int u = 0; u < 4; u++) {
            float v = adc[e + u];
            float nv = v - rm[i] - rm[j] + gm;
            adc[e + u] = nv;
            acc = fmaf(nv, nv, acc);
            if (j == 383) { ++i; j = i; } else ++j;
        }
    }
    __shared__ float red[4];
    float tsum = wave_reduce(acc);
    if (!(tid & 63)) red[tid >> 6] = tsum;
    __syncthreads();
    if (!tid) ws[WS_QPART + b * 8 + split] = red[0] + red[1] + red[2] + red[3];
}

// k5: DOTS[r][c] = dot(query row r, ctx row c). 40x40 tile, 1 wave, 5x5 microtile.
#define KCD 35
#define NSPL 96
#define KSL 770            // 73920 / 96
__global__ __launch_bounds__(64) void k_dots(const float* __restrict__ out,
                                             float* __restrict__ ws) {
    int rb = blockIdx.x;
    int cb = blockIdx.y;
    int ns = blockIdx.z;
    int tid = threadIdx.x;
    int tx = tid & 7, ty = tid >> 3;
    __shared__ float qsT[KCD][41];
    __shared__ float csT[KCD][41];
    const float* adc = out + OUT_ADC;
    int lo = ns * KSL;
    const float* qbase = adc + (size_t)(NSUP + rb * 40) * RTRI + lo;
    const float* cbase = adc + (size_t)(cb * 40) * RTRI + lo;
    float acc[5][5] = {};
    for (int k0 = 0; k0 < KSL; k0 += KCD) {
        for (int idx = tid; idx < 40 * KCD; idx += 64) {
            int r = idx / KCD, k = idx % KCD;
            qsT[k][r] = qbase[(size_t)r * RTRI + k0 + k];
            csT[k][r] = cbase[(size_t)r * RTRI + k0 + k];
        }
        __syncthreads();
        #pragma unroll 5
        for (int k = 0; k < KCD; k++) {
            float qa[5], ca[5];
            #pragma unroll
            for (int i = 0; i < 5; i++) qa[i] = qsT[k][ty * 5 + i];
            #pragma unroll
            for (int j = 0; j < 5; j++) ca[j] = csT[k][tx * 5 + j];
            #pragma unroll
            for (int i = 0; i < 5; i++)
                #pragma unroll
                for (int j = 0; j < 5; j++)
                    acc[i][j] = fmaf(qa[i], ca[j], acc[i][j]);
        }
        __syncthreads();
    }
    #pragma unroll
    for (int i = 0; i < 5; i++)
        #pragma unroll
        for (int j = 0; j < 5; j++)
            atomicAdd(&ws[WS_DOTS + (rb * 40 + ty * 5 + i) * 200 + cb * 40 + tx * 5 + j],
                      acc[i][j]);
}

// k5b: pn[c*8+f] = ||z_proto|| = sqrt(sum_{a,b} dot(ctx_a, ctx_b)) / 5
__global__ __launch_bounds__(256) void k_pn(const int* __restrict__ labels,
                                            const float* __restrict__ out,
                                            float* __restrict__ ws) {
    int o = blockIdx.x;      // c*8+f
    int c = o >> 3, f = o & 7;
    int tid = threadIdx.x;
    __shared__ int rows[5];
    if (tid == 0) {
        int cnt = 0;
        for (int s = 0; s < 25; s++)
            if (labels[s] == c && cnt < 5) rows[cnt++] = s * 8 + f;
    }
    __syncthreads();
    const float* adc = out + OUT_ADC;
    float acc[15] = {};
    for (int k = tid; k < RTRI; k += 256) {
        float v[5];
        #pragma unroll
        for (int a = 0; a < 5; a++) v[a] = adc[(size_t)rows[a] * RTRI + k];
        int idx = 0;
        #pragma unroll
        for (int a = 0; a < 5; a++)
            #pragma unroll
            for (int b2 = a; b2 < 5; b2++) {
                acc[idx] = fmaf(v[a], v[b2], acc[idx]);
                idx++;
            }
    }
    __shared__ float red[15];
    if (tid < 15) red[tid] = 0.f;
    __syncthreads();
    #pragma unroll
    for (int i = 0; i < 15; i++) {
        float t = wave_reduce(acc[i]);
        if (!(tid & 63)) atomicAdd(&red[i], t);
    }
    __syncthreads();
    if (tid == 0) {
        float tot = 0.f;
        int idx = 0;
        #pragma unroll
        for (int a = 0; a < 5; a++)
            #pragma unroll
            for (int b2 = a; b2 < 5; b2++) {
                tot += (a == b2) ? red[idx] : 2.f * red[idx];
                idx++;
            }
        ws[WS_PN + o] = fmaxf(sqrtf(fmaxf(tot, 0.f)) * 0.2f, 1e-8f);
    }
}

// k6: qn + ad from DOTS + QPART
__global__ __launch_bounds__(256) void k_post(const int* __restrict__ labels,
                                              float* __restrict__ ws) {
    __shared__ int mem[5][5];
    int tid = threadIdx.x;
    if (tid == 0) {
        int cnt[5] = {0,0,0,0,0};
        for (int s = 0; s < 25; s++) { int c = labels[s]; if (cnt[c] < 5) mem[c][cnt[c]++] = s; }
    }
    __syncthreads();
    for (int r = tid; r < 200; r += 256) {
        float ssum = 0.f;
        #pragma unroll
        for (int k = 0; k < 8; k++) ssum += ws[WS_QPART + (200 + r) * 8 + k];
        ws[WS_QN + r] = fmaxf(sqrtf(fmaxf(ssum, 0.f)), 1e-8f);
    }
    for (int idx = tid; idx < 8000; idx += 256) {
        int r = idx / 40, o = idx % 40;
        int c = o >> 3, f = o & 7;
        float s = 0.f;
        #pragma unroll
        for (int a = 0; a < 5; a++)
            s += ws[WS_DOTS + r * 200 + mem[c][a] * 8 + f];
        ws[WS_AD + idx] = s * 0.2f;
    }
}

// k7: proto[q] = mean_f(query cls) + mean_all(support cls)
__global__ __launch_bounds__(384) void k_proto(const float* __restrict__ lsn,
                                               float* __restrict__ ws) {
    int tid = threadIdx.x;
    float tsv = 0.f;
    for (int r = 0; r < 200; r++) tsv += lsn[(size_t)r * 197 * DIM + tid];
    tsv *= (1.0f / 200.0f);
    for (int q = 0; q < 25; q++) {
        float s = 0.f;
        #pragma unroll
        for (int f = 0; f < 8; f++) s += lsn[(size_t)(200 + q * 8 + f) * 197 * DIM + tid];
        ws[WS_PROTO + q * DIM + tid] = s * (1.0f / 8.0f) + tsv;
    }
}

// k8: tsm[q][g] = proto[q] . gen_weight[g]
__global__ __launch_bounds__(64) void k_tsm(const float* __restrict__ gw,
                                            float* __restrict__ ws) {
    int q = blockIdx.x, g = threadIdx.x;
    const float* pr = ws + WS_PROTO + q * DIM;
    const float* gr = gw + g * DIM;
    float s = 0.f;
    for (int d = 0; d < DIM; d++) s = fmaf(pr[d], gr[d], s);
    ws[WS_TSM + q * 64 + g] = s;
}

// k9: final score
__global__ __launch_bounds__(128) void k_score(const float* __restrict__ ws,
                                               float* __restrict__ out) {
    int t = threadIdx.x;
    if (t >= 125) return;
    int q = t / 5, wway = t % 5;
    float s = 0.f;
    for (int f = 0; f < 8; f++) {
        float qn = ws[WS_QN + q * 8 + f];
        for (int g = 0; g < 8; g++) {
            float ad = ws[WS_AD + (q * 8 + f) * 40 + wway * 8 + g];
            float pnv = ws[WS_PN + wway * 8 + g];
            s += (ad / (qn * pnv)) * ws[WS_TSM + q * 64 + f * 8 + g];
        }
    }
    out[OUT_SCORE + t] = s;
}

extern "C" void kernel_launch(void* const* d_in, const int* in_sizes, int n_in,
                              void* d_out, int out_size, void* d_ws, size_t ws_size,
                              hipStream_t stream) {
    const float* lsn = (const float*)d_in[0];
    const float* gw = (const float*)d_in[1];
    const int* labels = (const int*)d_in[2];
    float* ws = (float*)d_ws;
    float* out = (float*)d_out;

    {
        int n = (WS_AD - WS_RSUM);
        k_zero<<<dim3((n + 255) / 256), dim3(256), 0, stream>>>(ws + WS_RSUM, n);
    }
    k_prep<<<dim3(BATCH), dim3(384), 0, stream>>>(lsn, ws, out);
    k_gram<<<dim3(6, BATCH), dim3(256), 0, stream>>>(lsn, ws, out);
    k_rowmean<<<dim3(BATCH), dim3(384), 0, stream>>>(ws);
    k_center<<<dim3(8, BATCH), dim3(256), 0, stream>>>(ws, out);
    k_dots<<<dim3(5, 5, NSPL), dim3(64), 0, stream>>>(out, ws);
    k_pn<<<dim3(40), dim3(256), 0, stream>>>(labels, out, ws);
    k_post<<<1, dim3(256), 0, stream>>>(labels, ws);
    k_proto<<<1, dim3(384), 0, stream>>>(lsn, ws);
    k_tsm<<<dim3(25), dim3(64), 0, stream>>>(gw, ws);
    k_score<<<1, dim3(128), 0, stream>>>(ws, out);
}

// Round 7
// 657.952 us; speedup vs baseline: 1.3750x; 1.1405x over previous
//
#include <hip/hip_runtime.h>
#include <hip/hip_bf16.h>

#define BATCH 400
#define NPATCH 196
#define DIM 384
#define RTRI 73920          // 384*385/2
#define NSUP 200
#define OUT_SCORE 0
#define OUT_ADC 125
#define OUT_CLS (125 + BATCH * RTRI)

// ws offsets in floats (total 602880 floats = 2.41 MB)
#define WS_W      0         // 400*196  (holds w^2)
#define WS_SQ     78400     // 400*384
#define WS_RSUM   232000    // 400*384 (atomic; zeroed each launch)
#define WS_RM     385600    // 400*384
#define WS_GM     539200    // 400
#define WS_QPART  539600    // 400*8 (atomic-ish; zeroed)
#define WS_DOTS   542800    // 200*200 (atomic; zeroed)
#define WS_PNP    582800    // 40*16 (atomic; zeroed)
#define WS_AD     583440    // 200*40
#define WS_QN     591440    // 200
#define WS_PN     591640    // 40
#define WS_PROTO  591680    // 25*384
#define WS_TSM    601280    // 25*64
#define WS_TOTAL  602880

__device__ __forceinline__ float wave_reduce(float v) {
    #pragma unroll
    for (int o = 32; o; o >>= 1) v += __shfl_down(v, o);
    return v;
}

__global__ void k_zero(float* __restrict__ p, int n) {
    int i = blockIdx.x * 256 + threadIdx.x;
    if (i < n) p[i] = 0.f;
}

// k1: cosine weights w (stored squared), cls fp32 copy, sq[d] = diag of scaled Gram
__global__ __launch_bounds__(384) void k_prep(const float* __restrict__ lsn,
                                              float* __restrict__ ws,
                                              float* __restrict__ out) {
    int b = blockIdx.x, tid = threadIdx.x;
    __shared__ float clsL[DIM];
    __shared__ float wL[NPATCH];
    __shared__ float red[6];
    const float* base = lsn + (size_t)b * 197 * DIM;
    float c = base[tid];
    clsL[tid] = c;
    out[OUT_CLS + (size_t)b * DIM + tid] = c;
    float s = wave_reduce(c * c);
    int lane = tid & 63, wv = tid >> 6;
    if (!lane) red[wv] = s;
    __syncthreads();
    float clsn = fmaxf(sqrtf(red[0]+red[1]+red[2]+red[3]+red[4]+red[5]), 1e-8f);
    const float* patch = base + DIM;
    for (int p = wv; p < NPATCH; p += 6) {
        const float* pr = patch + p * DIM;
        float dot = 0.f, nsq = 0.f;
        #pragma unroll
        for (int t = 0; t < 6; t++) {
            float v = pr[lane + 64 * t];
            float cl = clsL[lane + 64 * t];
            dot = fmaf(v, cl, dot);
            nsq = fmaf(v, v, nsq);
        }
        dot = wave_reduce(dot);
        nsq = wave_reduce(nsq);
        if (!lane) {
            float val = dot / (clsn * fmaxf(sqrtf(nsq), 1e-8f));
            wL[p] = val;
            ws[WS_W + b * NPATCH + p] = val * val;   // store w^2 (k_gram folds into B)
        }
    }
    __syncthreads();
    float acc = 0.f;
    for (int m = 0; m < NPATCH; m++) {
        float v = wL[m] * patch[m * DIM + tid];
        acc = fmaf(v, v, acc);
    }
    ws[WS_SQ + b * DIM + tid] = acc * (1.0f / 392.0f);
}

// k2: fp32 Gram, 128x128 triu blocks, 8x8 microtile; A raw, B pre-scaled by w^2
#define TKG 28
#define LDG 132             // fp32 LDS stride (128+4)
__global__ __launch_bounds__(256) void k_gram(const float* __restrict__ lsn,
                                              float* __restrict__ ws,
                                              float* __restrict__ out) {
    int b = blockIdx.y;
    int t = blockIdx.x;                 // 0..5 -> triu (ti,tj) of 3x3
    int ti = (t < 3) ? 0 : ((t < 5) ? 1 : 2);
    int tj = (t < 3) ? t : ((t < 5) ? t - 2 : 2);

    __shared__ float As[TKG * LDG];
    __shared__ float Bs[TKG * LDG];

    int tid = threadIdx.x;
    int tx = tid & 15, ty = tid >> 4;

    const float* patch = lsn + (size_t)b * 197 * DIM + DIM;
    const float* wrow = ws + WS_W + b * NPATCH;   // w^2

    float acc[8][8] = {};
    for (int k0 = 0; k0 < NPATCH; k0 += TKG) {     // 7 steps of 28, exact
        for (int idx = tid; idx < TKG * 32; idx += 256) {   // 896 float4s per array
            int mi = idx >> 5, c4 = (idx & 31) * 4;
            const float* prow = patch + (size_t)(k0 + mi) * DIM;
            float4 a  = *(const float4*)&prow[ti * 128 + c4];
            float4 bv = *(const float4*)&prow[tj * 128 + c4];
            float w2 = wrow[k0 + mi];
            bv.x *= w2; bv.y *= w2; bv.z *= w2; bv.w *= w2;
            *(float4*)&As[mi * LDG + c4] = a;
            *(float4*)&Bs[mi * LDG + c4] = bv;
        }
        __syncthreads();
        #pragma unroll 4
        for (int k = 0; k < TKG; ++k) {
            float av[8], bv[8];
            *(float4*)&av[0] = *(const float4*)&As[k * LDG + ty * 8];
            *(float4*)&av[4] = *(const float4*)&As[k * LDG + ty * 8 + 4];
            *(float4*)&bv[0] = *(const float4*)&Bs[k * LDG + tx * 4];
            *(float4*)&bv[4] = *(const float4*)&Bs[k * LDG + 64 + tx * 4];
            #pragma unroll
            for (int i = 0; i < 8; i++)
                #pragma unroll
                for (int j = 0; j < 8; j++)
                    acc[i][j] = fmaf(av[i], bv[j], acc[i][j]);
        }
        __syncthreads();
    }

    // epilogue
    const float* sqb = ws + WS_SQ + b * DIM;
    int rb0 = ti * 128 + ty * 8;
    int cb0 = tj * 128;
    float sqi[8], sqj[8];
    #pragma unroll
    for (int i = 0; i < 8; i++) sqi[i] = sqb[rb0 + i];
    #pragma unroll
    for (int j = 0; j < 4; j++) {
        sqj[j]     = sqb[cb0 + tx * 4 + j];
        sqj[4 + j] = sqb[cb0 + 64 + tx * 4 + j];
    }

    float* adc = out + OUT_ADC + (size_t)b * RTRI;
    float rs[8] = {}, cs[8] = {};
    #pragma unroll
    for (int i = 0; i < 8; i++) {
        int gi = rb0 + i;
        #pragma unroll
        for (int j = 0; j < 8; j++) {
            int gj = cb0 + ((j < 4) ? (tx * 4 + j) : (64 + tx * 4 + (j - 4)));
            float dc = sqi[i] + sqj[j] - acc[i][j] * (1.0f / 196.0f);
            dc = fmaxf(dc, 0.f) + 1e-5f;
            float val = __expf(0.4f * __logf(dc));
            rs[i] += val;
            cs[j] += val;
            if (gj >= gi)
                adc[gi * (769 - gi) / 2 + (gj - gi)] = val;
        }
    }
    #pragma unroll
    for (int i = 0; i < 8; i++) {
        float v = rs[i];
        v += __shfl_xor(v, 1); v += __shfl_xor(v, 2);
        v += __shfl_xor(v, 4); v += __shfl_xor(v, 8);
        rs[i] = v;
    }
    if ((tid & 15) == 0) {
        #pragma unroll
        for (int i = 0; i < 8; i++)
            atomicAdd(&ws[WS_RSUM + b * DIM + rb0 + i], rs[i]);
    }
    if (ti != tj) {
        #pragma unroll
        for (int j = 0; j < 8; j++) {
            float v = cs[j];
            v += __shfl_xor(v, 16); v += __shfl_xor(v, 32);
            cs[j] = v;
        }
        if ((tid & 63) < 16) {
            #pragma unroll
            for (int j = 0; j < 8; j++) {
                int gj = cb0 + ((j < 4) ? (tx * 4 + j) : (64 + tx * 4 + (j - 4)));
                atomicAdd(&ws[WS_RSUM + b * DIM + gj], cs[j]);
            }
        }
    }
}

// k3: row means + grand mean
__global__ __launch_bounds__(384) void k_rowmean(float* __restrict__ ws) {
    int b = blockIdx.x, i = threadIdx.x;
    float s = ws[WS_RSUM + b * DIM + i];
    ws[WS_RM + b * DIM + i] = s * (1.0f / 384.0f);
    __shared__ float red[6];
    float tsum = wave_reduce(s);
    int lane = i & 63, wv = i >> 6;
    if (!lane) red[wv] = tsum;
    __syncthreads();
    if (i == 0) {
        float tot = red[0]+red[1]+red[2]+red[3]+red[4]+red[5];
        ws[WS_GM + b] = tot * (1.0f / (384.0f * 384.0f));
    }
}

// k4: in-place centering of adc (fp32), row-walk, + qnorm^2 partials
__global__ __launch_bounds__(256) void k_center(float* __restrict__ ws,
                                                float* __restrict__ out) {
    int s = blockIdx.x;       // row class i % 4 (load balance)
    int b = blockIdx.y;
    int tid = threadIdx.x;
    __shared__ float rmL[DIM];
    __shared__ float redL[4];
    const float* rm = ws + WS_RM + b * DIM;
    rmL[tid] = rm[tid];
    if (tid < DIM - 256) rmL[256 + tid] = rm[256 + tid];
    float gm = ws[WS_GM + b];
    __syncthreads();
    float* adc = out + OUT_ADC + (size_t)b * RTRI;
    float acc = 0.f;
    for (int i = s; i < DIM; i += 4) {
        int base = i * (769 - i) / 2;
        int L = DIM - i;
        float rmi = rmL[i] - gm;
        for (int off = tid; off < L; off += 256) {
            float v = adc[base + off];
            float nv = v - rmi - rmL[i + off];
            adc[base + off] = nv;
            acc = fmaf(nv, nv, acc);
        }
    }
    float t = wave_reduce(acc);
    if (!(tid & 63)) redL[tid >> 6] = t;
    __syncthreads();
    if (!tid) ws[WS_QPART + b * 8 + s] = redL[0] + redL[1] + redL[2] + redL[3];
}

// k5: DOTS[r][c] = dot(query row r, ctx row c). 40x40 tile, 1 wave, 5x5 microtile.
#define KCD 35
#define NSPL 96
#define KSL 770            // 73920 / 96
__global__ __launch_bounds__(64) void k_dots(const float* __restrict__ out,
                                             float* __restrict__ ws) {
    int rb = blockIdx.x;
    int cb = blockIdx.y;
    int ns = blockIdx.z;
    int tid = threadIdx.x;
    int tx = tid & 7, ty = tid >> 3;
    __shared__ float qsT[KCD][41];
    __shared__ float csT[KCD][41];
    const float* adc = out + OUT_ADC;
    int lo = ns * KSL;
    const float* qbase = adc + (size_t)(NSUP + rb * 40) * RTRI + lo;
    const float* cbase = adc + (size_t)(cb * 40) * RTRI + lo;
    float acc[5][5] = {};
    for (int k0 = 0; k0 < KSL; k0 += KCD) {
        for (int idx = tid; idx < 40 * KCD; idx += 64) {
            int r = idx / KCD, k = idx % KCD;
            qsT[k][r] = qbase[(size_t)r * RTRI + k0 + k];
            csT[k][r] = cbase[(size_t)r * RTRI + k0 + k];
        }
        __syncthreads();
        #pragma unroll 5
        for (int k = 0; k < KCD; k++) {
            float qa[5], ca[5];
            #pragma unroll
            for (int i = 0; i < 5; i++) qa[i] = qsT[k][ty * 5 + i];
            #pragma unroll
            for (int j = 0; j < 5; j++) ca[j] = csT[k][tx * 5 + j];
            #pragma unroll
            for (int i = 0; i < 5; i++)
                #pragma unroll
                for (int j = 0; j < 5; j++)
                    acc[i][j] = fmaf(qa[i], ca[j], acc[i][j]);
        }
        __syncthreads();
    }
    #pragma unroll
    for (int i = 0; i < 5; i++)
        #pragma unroll
        for (int j = 0; j < 5; j++)
            atomicAdd(&ws[WS_DOTS + (rb * 40 + ty * 5 + i) * 200 + cb * 40 + tx * 5 + j],
                      acc[i][j]);
}

// k5b: partial within-class ctx pair dots -> PNP[o][15], split-K
__global__ __launch_bounds__(256) void k_pn(const int* __restrict__ labels,
                                            const float* __restrict__ out,
                                            float* __restrict__ ws) {
    int o = blockIdx.x;      // c*8+f
    int sp = blockIdx.y;     // 0..7 K split
    int c = o >> 3, f = o & 7;
    int tid = threadIdx.x;
    __shared__ int rows[5];
    if (tid == 0) {
        int cnt = 0;
        for (int s = 0; s < 25; s++)
            if (labels[s] == c && cnt < 5) rows[cnt++] = s * 8 + f;
    }
    __syncthreads();
    const float* adc = out + OUT_ADC;
    float acc[15] = {};
    int lo = sp * 9240, hi = lo + 9240;
    for (int k = lo + tid; k < hi; k += 256) {
        float v[5];
        #pragma unroll
        for (int a = 0; a < 5; a++) v[a] = adc[(size_t)rows[a] * RTRI + k];
        int idx = 0;
        #pragma unroll
        for (int a = 0; a < 5; a++)
            #pragma unroll
            for (int b2 = a; b2 < 5; b2++) {
                acc[idx] = fmaf(v[a], v[b2], acc[idx]);
                idx++;
            }
    }
    __shared__ float red[15];
    if (tid < 15) red[tid] = 0.f;
    __syncthreads();
    #pragma unroll
    for (int i = 0; i < 15; i++) {
        float t = wave_reduce(acc[i]);
        if (!(tid & 63)) atomicAdd(&red[i], t);
    }
    __syncthreads();
    if (tid < 15) atomicAdd(&ws[WS_PNP + o * 16 + tid], red[tid]);
}

// k6: qn + pn finalize + ad from DOTS/PNP/QPART
__global__ __launch_bounds__(256) void k_post(const int* __restrict__ labels,
                                              float* __restrict__ ws) {
    __shared__ int mem[5][5];
    int tid = threadIdx.x;
    if (tid == 0) {
        int cnt[5] = {0,0,0,0,0};
        for (int s = 0; s < 25; s++) { int c = labels[s]; if (cnt[c] < 5) mem[c][cnt[c]++] = s; }
    }
    __syncthreads();
    for (int r = tid; r < 200; r += 256) {
        float ssum = 0.f;
        #pragma unroll
        for (int k = 0; k < 8; k++) ssum += ws[WS_QPART + (200 + r) * 8 + k];
        ws[WS_QN + r] = fmaxf(sqrtf(fmaxf(ssum, 0.f)), 1e-8f);
    }
    if (tid < 40) {
        float tot = 0.f;
        int idx = 0;
        #pragma unroll
        for (int a = 0; a < 5; a++)
            #pragma unroll
            for (int b2 = a; b2 < 5; b2++) {
                tot += ((a == b2) ? 1.f : 2.f) * ws[WS_PNP + tid * 16 + idx];
                idx++;
            }
        ws[WS_PN + tid] = fmaxf(sqrtf(fmaxf(tot, 0.f)) * 0.2f, 1e-8f);
    }
    __syncthreads();
    for (int idx = tid; idx < 8000; idx += 256) {
        int r = idx / 40, o = idx % 40;
        int c = o >> 3, f = o & 7;
        float s = 0.f;
        #pragma unroll
        for (int a = 0; a < 5; a++)
            s += ws[WS_DOTS + r * 200 + mem[c][a] * 8 + f];
        ws[WS_AD + idx] = s * 0.2f;
    }
}

// k7: proto[q] = mean_f(query cls) + mean_all(support cls)
__global__ __launch_bounds__(384) void k_proto(const float* __restrict__ lsn,
                                               float* __restrict__ ws) {
    int tid = threadIdx.x;
    float tsv = 0.f;
    for (int r = 0; r < 200; r++) tsv += lsn[(size_t)r * 197 * DIM + tid];
    tsv *= (1.0f / 200.0f);
    for (int q = 0; q < 25; q++) {
        float s = 0.f;
        #pragma unroll
        for (int f = 0; f < 8; f++) s += lsn[(size_t)(200 + q * 8 + f) * 197 * DIM + tid];
        ws[WS_PROTO + q * DIM + tid] = s * (1.0f / 8.0f) + tsv;
    }
}

// k8: tsm[q][g] = proto[q] . gen_weight[g]
__global__ __launch_bounds__(64) void k_tsm(const float* __restrict__ gw,
                                            float* __restrict__ ws) {
    int q = blockIdx.x, g = threadIdx.x;
    const float* pr = ws + WS_PROTO + q * DIM;
    const float* gr = gw + g * DIM;
    float s = 0.f;
    for (int d = 0; d < DIM; d++) s = fmaf(pr[d], gr[d], s);
    ws[WS_TSM + q * 64 + g] = s;
}

// k9: final score
__global__ __launch_bounds__(128) void k_score(const float* __restrict__ ws,
                                               float* __restrict__ out) {
    int t = threadIdx.x;
    if (t >= 125) return;
    int q = t / 5, wway = t % 5;
    float s = 0.f;
    for (int f = 0; f < 8; f++) {
        float qn = ws[WS_QN + q * 8 + f];
        for (int g = 0; g < 8; g++) {
            float ad = ws[WS_AD + (q * 8 + f) * 40 + wway * 8 + g];
            float pnv = ws[WS_PN + wway * 8 + g];
            s += (ad / (qn * pnv)) * ws[WS_TSM + q * 64 + f * 8 + g];
        }
    }
    out[OUT_SCORE + t] = s;
}

extern "C" void kernel_launch(void* const* d_in, const int* in_sizes, int n_in,
                              void* d_out, int out_size, void* d_ws, size_t ws_size,
                              hipStream_t stream) {
    const float* lsn = (const float*)d_in[0];
    const float* gw = (const float*)d_in[1];
    const int* labels = (const int*)d_in[2];
    float* ws = (float*)d_ws;
    float* out = (float*)d_out;

    {
        int n = (WS_AD - WS_RSUM);   // RSUM, RM, GM, QPART, DOTS, PNP
        k_zero<<<dim3((n + 255) / 256), dim3(256), 0, stream>>>(ws + WS_RSUM, n);
    }
    k_prep<<<dim3(BATCH), dim3(384), 0, stream>>>(lsn, ws, out);
    k_gram<<<dim3(6, BATCH), dim3(256), 0, stream>>>(lsn, ws, out);
    k_rowmean<<<dim3(BATCH), dim3(384), 0, stream>>>(ws);
    k_center<<<dim3(4, BATCH), dim3(256), 0, stream>>>(ws, out);
    k_dots<<<dim3(5, 5, NSPL), dim3(64), 0, stream>>>(out, ws);
    k_pn<<<dim3(40, 8), dim3(256), 0, stream>>>(labels, out, ws);
    k_post<<<1, dim3(256), 0, stream>>>(labels, ws);
    k_proto<<<1, dim3(384), 0, stream>>>(lsn, ws);
    k_tsm<<<dim3(25), dim3(64), 0, stream>>>(gw, ws);
    k_score<<<1, dim3(128), 0, stream>>>(ws, out);
}

// Round 8
// 520.097 us; speedup vs baseline: 1.7395x; 1.2651x over previous
//
#include <hip/hip_runtime.h>
#include <hip/hip_bf16.h>

#define BATCH 400
#define NPATCH 196
#define DIM 384
#define RTRI 73920          // 384*385/2
#define NSUP 200
#define OUT_SCORE 0
#define OUT_ADC 125
#define OUT_CLS (125 + BATCH * RTRI)

// ws offsets in floats (total 602880 floats = 2.41 MB)
#define WS_W      0         // 400*196  (holds w^2)
#define WS_SQ     78400     // 400*384
#define WS_RSUM   232000    // 400*384 (atomic; zeroed each launch)
#define WS_RM     385600    // 400*384
#define WS_GM     539200    // 400
#define WS_QPART  539600    // 400*8 (zeroed)
#define WS_DOTS   542800    // 200*200 (atomic; zeroed)
#define WS_PNP    582800    // 40*16 (atomic; zeroed)
#define WS_AD     583440    // 200*40
#define WS_QN     591440    // 200
#define WS_PN     591640    // 40
#define WS_PROTO  591680    // 25*384
#define WS_TSM    601280    // 25*64
#define WS_TOTAL  602880

typedef __attribute__((ext_vector_type(8))) short bf16x8;
typedef __attribute__((ext_vector_type(4))) short short4v;
typedef __attribute__((ext_vector_type(4))) float f32x4;

__device__ __forceinline__ float wave_reduce(float v) {
    #pragma unroll
    for (int o = 32; o; o >>= 1) v += __shfl_down(v, o);
    return v;
}

__device__ __forceinline__ unsigned short f2bf(float f) {
    unsigned int x = __float_as_uint(f);
    x += 0x7FFFu + ((x >> 16) & 1u);    // RNE
    return (unsigned short)(x >> 16);
}

__global__ void k_zero(float* __restrict__ p, int n) {
    int i = blockIdx.x * 256 + threadIdx.x;
    if (i < n) p[i] = 0.f;
}

// k1: cosine weights w (stored squared), cls fp32 copy, sq[d] = diag of scaled Gram
__global__ __launch_bounds__(384) void k_prep(const float* __restrict__ lsn,
                                              float* __restrict__ ws,
                                              float* __restrict__ out) {
    int b = blockIdx.x, tid = threadIdx.x;
    __shared__ float clsL[DIM];
    __shared__ float wL[NPATCH];
    __shared__ float red[6];
    const float* base = lsn + (size_t)b * 197 * DIM;
    float c = base[tid];
    clsL[tid] = c;
    out[OUT_CLS + (size_t)b * DIM + tid] = c;
    float s = wave_reduce(c * c);
    int lane = tid & 63, wv = tid >> 6;
    if (!lane) red[wv] = s;
    __syncthreads();
    float clsn = fmaxf(sqrtf(red[0]+red[1]+red[2]+red[3]+red[4]+red[5]), 1e-8f);
    const float* patch = base + DIM;
    for (int p = wv; p < NPATCH; p += 6) {
        const float* pr = patch + p * DIM;
        float dot = 0.f, nsq = 0.f;
        #pragma unroll
        for (int t = 0; t < 6; t++) {
            float v = pr[lane + 64 * t];
            float cl = clsL[lane + 64 * t];
            dot = fmaf(v, cl, dot);
            nsq = fmaf(v, v, nsq);
        }
        dot = wave_reduce(dot);
        nsq = wave_reduce(nsq);
        if (!lane) {
            float val = dot / (clsn * fmaxf(sqrtf(nsq), 1e-8f));
            wL[p] = val;
            ws[WS_W + b * NPATCH + p] = val * val;   // store w^2 (k_gram folds into B)
        }
    }
    __syncthreads();
    float acc = 0.f;
    for (int m = 0; m < NPATCH; m++) {
        float v = wL[m] * patch[m * DIM + tid];
        acc = fmaf(v, v, acc);
    }
    ws[WS_SQ + b * DIM + tid] = acc * (1.0f / 392.0f);
}

// k2: fp32 Gram, 128x128 triu blocks, 8x8 microtile; A raw, B pre-scaled by w^2
#define TKG 28
#define LDG 132             // fp32 LDS stride (128+4)
__global__ __launch_bounds__(256) void k_gram(const float* __restrict__ lsn,
                                              float* __restrict__ ws,
                                              float* __restrict__ out) {
    int b = blockIdx.y;
    int t = blockIdx.x;                 // 0..5 -> triu (ti,tj) of 3x3
    int ti = (t < 3) ? 0 : ((t < 5) ? 1 : 2);
    int tj = (t < 3) ? t : ((t < 5) ? t - 2 : 2);

    __shared__ float As[TKG * LDG];
    __shared__ float Bs[TKG * LDG];

    int tid = threadIdx.x;
    int tx = tid & 15, ty = tid >> 4;

    const float* patch = lsn + (size_t)b * 197 * DIM + DIM;
    const float* wrow = ws + WS_W + b * NPATCH;   // w^2

    float acc[8][8] = {};
    for (int k0 = 0; k0 < NPATCH; k0 += TKG) {     // 7 steps of 28, exact
        for (int idx = tid; idx < TKG * 32; idx += 256) {   // 896 float4s per array
            int mi = idx >> 5, c4 = (idx & 31) * 4;
            const float* prow = patch + (size_t)(k0 + mi) * DIM;
            float4 a  = *(const float4*)&prow[ti * 128 + c4];
            float4 bv = *(const float4*)&prow[tj * 128 + c4];
            float w2 = wrow[k0 + mi];
            bv.x *= w2; bv.y *= w2; bv.z *= w2; bv.w *= w2;
            *(float4*)&As[mi * LDG + c4] = a;
            *(float4*)&Bs[mi * LDG + c4] = bv;
        }
        __syncthreads();
        #pragma unroll 4
        for (int k = 0; k < TKG; ++k) {
            float av[8], bv[8];
            *(float4*)&av[0] = *(const float4*)&As[k * LDG + ty * 8];
            *(float4*)&av[4] = *(const float4*)&As[k * LDG + ty * 8 + 4];
            *(float4*)&bv[0] = *(const float4*)&Bs[k * LDG + tx * 4];
            *(float4*)&bv[4] = *(const float4*)&Bs[k * LDG + 64 + tx * 4];
            #pragma unroll
            for (int i = 0; i < 8; i++)
                #pragma unroll
                for (int j = 0; j < 8; j++)
                    acc[i][j] = fmaf(av[i], bv[j], acc[i][j]);
        }
        __syncthreads();
    }

    // epilogue
    const float* sqb = ws + WS_SQ + b * DIM;
    int rb0 = ti * 128 + ty * 8;
    int cb0 = tj * 128;
    float sqi[8], sqj[8];
    #pragma unroll
    for (int i = 0; i < 8; i++) sqi[i] = sqb[rb0 + i];
    #pragma unroll
    for (int j = 0; j < 4; j++) {
        sqj[j]     = sqb[cb0 + tx * 4 + j];
        sqj[4 + j] = sqb[cb0 + 64 + tx * 4 + j];
    }

    float* adc = out + OUT_ADC + (size_t)b * RTRI;
    float rs[8] = {}, cs[8] = {};
    #pragma unroll
    for (int i = 0; i < 8; i++) {
        int gi = rb0 + i;
        #pragma unroll
        for (int j = 0; j < 8; j++) {
            int gj = cb0 + ((j < 4) ? (tx * 4 + j) : (64 + tx * 4 + (j - 4)));
            float dc = sqi[i] + sqj[j] - acc[i][j] * (1.0f / 196.0f);
            dc = fmaxf(dc, 0.f) + 1e-5f;
            float val = __expf(0.4f * __logf(dc));
            rs[i] += val;
            cs[j] += val;
            if (gj >= gi)
                adc[gi * (769 - gi) / 2 + (gj - gi)] = val;
        }
    }
    #pragma unroll
    for (int i = 0; i < 8; i++) {
        float v = rs[i];
        v += __shfl_xor(v, 1); v += __shfl_xor(v, 2);
        v += __shfl_xor(v, 4); v += __shfl_xor(v, 8);
        rs[i] = v;
    }
    if ((tid & 15) == 0) {
        #pragma unroll
        for (int i = 0; i < 8; i++)
            atomicAdd(&ws[WS_RSUM + b * DIM + rb0 + i], rs[i]);
    }
    if (ti != tj) {
        #pragma unroll
        for (int j = 0; j < 8; j++) {
            float v = cs[j];
            v += __shfl_xor(v, 16); v += __shfl_xor(v, 32);
            cs[j] = v;
        }
        if ((tid & 63) < 16) {
            #pragma unroll
            for (int j = 0; j < 8; j++) {
                int gj = cb0 + ((j < 4) ? (tx * 4 + j) : (64 + tx * 4 + (j - 4)));
                atomicAdd(&ws[WS_RSUM + b * DIM + gj], cs[j]);
            }
        }
    }
}

// k3: row means + grand mean
__global__ __launch_bounds__(384) void k_rowmean(float* __restrict__ ws) {
    int b = blockIdx.x, i = threadIdx.x;
    float s = ws[WS_RSUM + b * DIM + i];
    ws[WS_RM + b * DIM + i] = s * (1.0f / 384.0f);
    __shared__ float red[6];
    float tsum = wave_reduce(s);
    int lane = i & 63, wv = i >> 6;
    if (!lane) red[wv] = tsum;
    __syncthreads();
    if (i == 0) {
        float tot = red[0]+red[1]+red[2]+red[3]+red[4]+red[5];
        ws[WS_GM + b] = tot * (1.0f / (384.0f * 384.0f));
    }
}

// k4: in-place centering of adc (fp32), row-walk, + qnorm^2 partials
__global__ __launch_bounds__(256) void k_center(float* __restrict__ ws,
                                                float* __restrict__ out) {
    int s = blockIdx.x;       // row class i % 4 (load balance)
    int b = blockIdx.y;
    int tid = threadIdx.x;
    __shared__ float rmL[DIM];
    __shared__ float redL[4];
    const float* rm = ws + WS_RM + b * DIM;
    rmL[tid] = rm[tid];
    if (tid < DIM - 256) rmL[256 + tid] = rm[256 + tid];
    float gm = ws[WS_GM + b];
    __syncthreads();
    float* adc = out + OUT_ADC + (size_t)b * RTRI;
    float acc = 0.f;
    for (int i = s; i < DIM; i += 4) {
        int base = i * (769 - i) / 2;
        int L = DIM - i;
        float rmi = rmL[i] - gm;
        for (int off = tid; off < L; off += 256) {
            float v = adc[base + off];
            float nv = v - rmi - rmL[i + off];
            adc[base + off] = nv;
            acc = fmaf(nv, nv, acc);
        }
    }
    float t = wave_reduce(acc);
    if (!(tid & 63)) redL[tid >> 6] = t;
    __syncthreads();
    if (!tid) ws[WS_QPART + b * 8 + s] = redL[0] + redL[1] + redL[2] + redL[3];
}

// k5: DOTS[r][c] = dot(query r, ctx c) via split-K bf16 MFMA.
// grid (2,2,NS2): 104x104 output quadrant (padded 128x128), 8 waves (2x4).
#define DKD 32              // K per step
#define LDK 40              // LDS stride in bf16 (80 B: 2-way max aliasing)
#define NS2 66
#define CHB 35              // chunks per block: 66*35*32 = 73920
__global__ __launch_bounds__(512) void k_dots(const float* __restrict__ out,
                                              float* __restrict__ ws) {
    int qi = blockIdx.x, qj = blockIdx.y, ns = blockIdx.z;
    int tid = threadIdx.x;
    int lane = tid & 63, w = tid >> 6;
    int wr = w >> 2, wc = w & 3;        // 2x4 waves: 64 rows x 32 cols each
    __shared__ __align__(16) unsigned short As[128 * LDK];
    __shared__ __align__(16) unsigned short Bs[128 * LDK];
    const float* adc = out + OUT_ADC;
    int realA = (qi == 0) ? 104 : 96;
    int realB = (qj == 0) ? 104 : 96;
    const float* qb = adc + (size_t)(NSUP + qi * 104) * RTRI;
    const float* cb = adc + (size_t)(qj * 104) * RTRI;

    f32x4 acc[4][2] = {};
    for (int ck = 0; ck < CHB; ++ck) {
        int k0 = (ns * CHB + ck) * DKD;
        // stage 128 rows x 32 k for A and B (2048 float4-tasks / 512 thr = 4)
        #pragma unroll
        for (int it = 0; it < 4; ++it) {
            int idx = tid + it * 512;
            int arr = idx >> 10;
            int r = (idx >> 3) & 127;
            int kq = (idx & 7) << 2;
            const float* src = arr ? cb : qb;
            int real = arr ? realB : realA;
            float4 v = make_float4(0.f, 0.f, 0.f, 0.f);
            if (r < real) v = *(const float4*)&src[(size_t)r * RTRI + k0 + kq];
            short4v sv;
            sv[0] = (short)f2bf(v.x); sv[1] = (short)f2bf(v.y);
            sv[2] = (short)f2bf(v.z); sv[3] = (short)f2bf(v.w);
            unsigned short* dst = arr ? Bs : As;
            *(short4v*)&dst[r * LDK + kq] = sv;
        }
        __syncthreads();
        int kb = (lane >> 4) * 8;
        bf16x8 af[4], bfv[2];
        #pragma unroll
        for (int tr = 0; tr < 4; ++tr)
            af[tr] = *(const bf16x8*)&As[(wr * 64 + tr * 16 + (lane & 15)) * LDK + kb];
        #pragma unroll
        for (int tc = 0; tc < 2; ++tc)
            bfv[tc] = *(const bf16x8*)&Bs[(wc * 32 + tc * 16 + (lane & 15)) * LDK + kb];
        #pragma unroll
        for (int tr = 0; tr < 4; ++tr)
            #pragma unroll
            for (int tc = 0; tc < 2; ++tc)
                acc[tr][tc] = __builtin_amdgcn_mfma_f32_16x16x32_bf16(
                    af[tr], bfv[tc], acc[tr][tc], 0, 0, 0);
        __syncthreads();
    }
    #pragma unroll
    for (int tr = 0; tr < 4; ++tr)
        #pragma unroll
        for (int tc = 0; tc < 2; ++tc)
            #pragma unroll
            for (int rg = 0; rg < 4; ++rg) {
                int lr = wr * 64 + tr * 16 + (lane >> 4) * 4 + rg;
                int lc = wc * 32 + tc * 16 + (lane & 15);
                if (lr < realA && lc < realB)
                    atomicAdd(&ws[WS_DOTS + (qi * 104 + lr) * 200 + (qj * 104 + lc)],
                              acc[tr][tc][rg]);
            }
}

// k5b: partial within-class ctx pair dots -> PNP[o][15], split-K
__global__ __launch_bounds__(256) void k_pn(const int* __restrict__ labels,
                                            const float* __restrict__ out,
                                            float* __restrict__ ws) {
    int o = blockIdx.x;      // c*8+f
    int sp = blockIdx.y;     // 0..7 K split
    int c = o >> 3, f = o & 7;
    int tid = threadIdx.x;
    __shared__ int rows[5];
    if (tid == 0) {
        int cnt = 0;
        for (int s = 0; s < 25; s++)
            if (labels[s] == c && cnt < 5) rows[cnt++] = s * 8 + f;
    }
    __syncthreads();
    const float* adc = out + OUT_ADC;
    float acc[15] = {};
    int lo = sp * 9240, hi = lo + 9240;
    for (int k = lo + tid; k < hi; k += 256) {
        float v[5];
        #pragma unroll
        for (int a = 0; a < 5; a++) v[a] = adc[(size_t)rows[a] * RTRI + k];
        int idx = 0;
        #pragma unroll
        for (int a = 0; a < 5; a++)
            #pragma unroll
            for (int b2 = a; b2 < 5; b2++) {
                acc[idx] = fmaf(v[a], v[b2], acc[idx]);
                idx++;
            }
    }
    __shared__ float red[15];
    if (tid < 15) red[tid] = 0.f;
    __syncthreads();
    #pragma unroll
    for (int i = 0; i < 15; i++) {
        float t = wave_reduce(acc[i]);
        if (!(tid & 63)) atomicAdd(&red[i], t);
    }
    __syncthreads();
    if (tid < 15) atomicAdd(&ws[WS_PNP + o * 16 + tid], red[tid]);
}

// k6: qn + pn finalize + ad from DOTS/PNP/QPART
__global__ __launch_bounds__(256) void k_post(const int* __restrict__ labels,
                                              float* __restrict__ ws) {
    __shared__ int mem[5][5];
    int tid = threadIdx.x;
    if (tid == 0) {
        int cnt[5] = {0,0,0,0,0};
        for (int s = 0; s < 25; s++) { int c = labels[s]; if (cnt[c] < 5) mem[c][cnt[c]++] = s; }
    }
    __syncthreads();
    for (int r = tid; r < 200; r += 256) {
        float ssum = 0.f;
        #pragma unroll
        for (int k = 0; k < 8; k++) ssum += ws[WS_QPART + (200 + r) * 8 + k];
        ws[WS_QN + r] = fmaxf(sqrtf(fmaxf(ssum, 0.f)), 1e-8f);
    }
    if (tid < 40) {
        float tot = 0.f;
        int idx = 0;
        #pragma unroll
        for (int a = 0; a < 5; a++)
            #pragma unroll
            for (int b2 = a; b2 < 5; b2++) {
                tot += ((a == b2) ? 1.f : 2.f) * ws[WS_PNP + tid * 16 + idx];
                idx++;
            }
        ws[WS_PN + tid] = fmaxf(sqrtf(fmaxf(tot, 0.f)) * 0.2f, 1e-8f);
    }
    __syncthreads();
    for (int idx = tid; idx < 8000; idx += 256) {
        int r = idx / 40, o = idx % 40;
        int c = o >> 3, f = o & 7;
        float s = 0.f;
        #pragma unroll
        for (int a = 0; a < 5; a++)
            s += ws[WS_DOTS + r * 200 + mem[c][a] * 8 + f];
        ws[WS_AD + idx] = s * 0.2f;
    }
}

// k7: proto[q] = mean_f(query cls) + mean_all(support cls)
__global__ __launch_bounds__(384) void k_proto(const float* __restrict__ lsn,
                                               float* __restrict__ ws) {
    int tid = threadIdx.x;
    float tsv = 0.f;
    for (int r = 0; r < 200; r++) tsv += lsn[(size_t)r * 197 * DIM + tid];
    tsv *= (1.0f / 200.0f);
    for (int q = 0; q < 25; q++) {
        float s = 0.f;
        #pragma unroll
        for (int f = 0; f < 8; f++) s += lsn[(size_t)(200 + q * 8 + f) * 197 * DIM + tid];
        ws[WS_PROTO + q * DIM + tid] = s * (1.0f / 8.0f) + tsv;
    }
}

// k8: tsm[q][g] = proto[q] . gen_weight[g]
__global__ __launch_bounds__(64) void k_tsm(const float* __restrict__ gw,
                                            float* __restrict__ ws) {
    int q = blockIdx.x, g = threadIdx.x;
    const float* pr = ws + WS_PROTO + q * DIM;
    const float* gr = gw + g * DIM;
    float s = 0.f;
    for (int d = 0; d < DIM; d++) s = fmaf(pr[d], gr[d], s);
    ws[WS_TSM + q * 64 + g] = s;
}

// k9: final score
__global__ __launch_bounds__(128) void k_score(const float* __restrict__ ws,
                                               float* __restrict__ out) {
    int t = threadIdx.x;
    if (t >= 125) return;
    int q = t / 5, wway = t % 5;
    float s = 0.f;
    for (int f = 0; f < 8; f++) {
        float qn = ws[WS_QN + q * 8 + f];
        for (int g = 0; g < 8; g++) {
            float ad = ws[WS_AD + (q * 8 + f) * 40 + wway * 8 + g];
            float pnv = ws[WS_PN + wway * 8 + g];
            s += (ad / (qn * pnv)) * ws[WS_TSM + q * 64 + f * 8 + g];
        }
    }
    out[OUT_SCORE + t] = s;
}

extern "C" void kernel_launch(void* const* d_in, const int* in_sizes, int n_in,
                              void* d_out, int out_size, void* d_ws, size_t ws_size,
                              hipStream_t stream) {
    const float* lsn = (const float*)d_in[0];
    const float* gw = (const float*)d_in[1];
    const int* labels = (const int*)d_in[2];
    float* ws = (float*)d_ws;
    float* out = (float*)d_out;

    {
        int n = (WS_AD - WS_RSUM);   // RSUM, RM, GM, QPART, DOTS, PNP
        k_zero<<<dim3((n + 255) / 256), dim3(256), 0, stream>>>(ws + WS_RSUM, n);
    }
    k_prep<<<dim3(BATCH), dim3(384), 0, stream>>>(lsn, ws, out);
    k_gram<<<dim3(6, BATCH), dim3(256), 0, stream>>>(lsn, ws, out);
    k_rowmean<<<dim3(BATCH), dim3(384), 0, stream>>>(ws);
    k_center<<<dim3(4, BATCH), dim3(256), 0, stream>>>(ws, out);
    k_dots<<<dim3(2, 2, NS2), dim3(512), 0, stream>>>(out, ws);
    k_pn<<<dim3(40, 8), dim3(256), 0, stream>>>(labels, out, ws);
    k_post<<<1, dim3(256), 0, stream>>>(labels, ws);
    k_proto<<<1, dim3(384), 0, stream>>>(lsn, ws);
    k_tsm<<<dim3(25), dim3(64), 0, stream>>>(gw, ws);
    k_score<<<1, dim3(128), 0, stream>>>(ws, out);
}

// Round 9
// 462.579 us; speedup vs baseline: 1.9558x; 1.1243x over previous
//
#include <hip/hip_runtime.h>
#include <hip/hip_bf16.h>

#define BATCH 400
#define NPATCH 196
#define DIM 384
#define RTRI 73920          // 384*385/2
#define NSUP 200
#define OUT_SCORE 0
#define OUT_ADC 125
#define OUT_CLS (125 + BATCH * RTRI)

// ws offsets in floats (total 602880 floats = 2.41 MB)
#define WS_W      0         // 400*196  (holds w^2)
#define WS_SQ     78400     // 400*384
#define WS_RSUM   232000    // 400*384 (atomic; zeroed each launch)
#define WS_RM     385600    // 400*384
#define WS_GM     539200    // 400
#define WS_QPART  539600    // 400*8 (zeroed)
#define WS_DOTS   542800    // 200*200 (atomic; zeroed)
#define WS_PNP    582800    // 40*16 (atomic; zeroed)
#define WS_AD     583440    // 200*40
#define WS_QN     591440    // 200
#define WS_PN     591640    // 40
#define WS_PROTO  591680    // 25*384
#define WS_TSM    601280    // 25*64
#define WS_TOTAL  602880

typedef __attribute__((ext_vector_type(8))) short bf16x8;
typedef __attribute__((ext_vector_type(4))) short short4v;
typedef __attribute__((ext_vector_type(4))) float f32x4;

__device__ __forceinline__ float wave_reduce(float v) {
    #pragma unroll
    for (int o = 32; o; o >>= 1) v += __shfl_down(v, o);
    return v;
}

__device__ __forceinline__ unsigned short f2bf(float f) {
    unsigned int x = __float_as_uint(f);
    x += 0x7FFFu + ((x >> 16) & 1u);    // RNE
    return (unsigned short)(x >> 16);
}

__global__ void k_zero(float* __restrict__ p, int n) {
    int i = blockIdx.x * 256 + threadIdx.x;
    if (i < n) p[i] = 0.f;
}

// k1: cosine weights w (stored squared), cls fp32 copy, sq[d] = diag of scaled Gram
__global__ __launch_bounds__(384) void k_prep(const float* __restrict__ lsn,
                                              float* __restrict__ ws,
                                              float* __restrict__ out) {
    int b = blockIdx.x, tid = threadIdx.x;
    __shared__ float clsL[DIM];
    __shared__ float wL[NPATCH];
    __shared__ float red[6];
    const float* base = lsn + (size_t)b * 197 * DIM;
    float c = base[tid];
    clsL[tid] = c;
    out[OUT_CLS + (size_t)b * DIM + tid] = c;
    float s = wave_reduce(c * c);
    int lane = tid & 63, wv = tid >> 6;
    if (!lane) red[wv] = s;
    __syncthreads();
    float clsn = fmaxf(sqrtf(red[0]+red[1]+red[2]+red[3]+red[4]+red[5]), 1e-8f);
    const float* patch = base + DIM;
    for (int p = wv; p < NPATCH; p += 6) {
        const float* pr = patch + p * DIM;
        float dot = 0.f, nsq = 0.f;
        #pragma unroll
        for (int t = 0; t < 6; t++) {
            float v = pr[lane + 64 * t];
            float cl = clsL[lane + 64 * t];
            dot = fmaf(v, cl, dot);
            nsq = fmaf(v, v, nsq);
        }
        dot = wave_reduce(dot);
        nsq = wave_reduce(nsq);
        if (!lane) {
            float val = dot / (clsn * fmaxf(sqrtf(nsq), 1e-8f));
            wL[p] = val;
            ws[WS_W + b * NPATCH + p] = val * val;   // store w^2 (k_gram folds into B)
        }
    }
    __syncthreads();
    float acc = 0.f;
    for (int m = 0; m < NPATCH; m++) {
        float v = wL[m] * patch[m * DIM + tid];
        acc = fmaf(v, v, acc);
    }
    ws[WS_SQ + b * DIM + tid] = acc * (1.0f / 392.0f);
}

// k2: bf16 MFMA Gram, 128x128 triu blocks, 2x2 waves of 64x64.
// LDS [m][d] (LDM=132 pad); fragments gathered via scalar u16 reads.
#define LDM 132
__global__ __launch_bounds__(256) void k_gram(const float* __restrict__ lsn,
                                              float* __restrict__ ws,
                                              float* __restrict__ out) {
    int b = blockIdx.y;
    int t = blockIdx.x;                 // 0..5 -> triu (ti,tj) of 3x3
    int ti = (t < 3) ? 0 : ((t < 5) ? 1 : 2);
    int tj = (t < 3) ? t : ((t < 5) ? t - 2 : 2);

    __shared__ __align__(16) unsigned short As[32 * LDM];
    __shared__ __align__(16) unsigned short Bs[32 * LDM];

    int tid = threadIdx.x;
    int lane = tid & 63, w = tid >> 6;
    int wr = w >> 1, wc = w & 1;        // 2x2 waves, each 64x64

    const float* patch = lsn + (size_t)b * 197 * DIM + DIM;
    const float* wrow = ws + WS_W + b * NPATCH;   // w^2

    f32x4 acc[4][4] = {};

    for (int k0 = 0; k0 < 224; k0 += 32) {   // 7 ksteps; rows >=196 zero-padded
        #pragma unroll
        for (int it = 0; it < 8; ++it) {     // 2048 float4 tasks / 256 threads
            int idx = tid + it * 256;
            int arr = idx >> 10;             // 0: A(ti, raw), 1: B(tj, *w^2)
            int m = (idx >> 5) & 31;
            int c4 = (idx & 31) * 4;
            int mg = k0 + m;
            short4v sv;
            if (mg < NPATCH) {
                int dbase = (arr ? tj : ti) * 128 + c4;
                float4 v = *(const float4*)&patch[(size_t)mg * DIM + dbase];
                if (arr) {
                    float w2 = wrow[mg];
                    v.x *= w2; v.y *= w2; v.z *= w2; v.w *= w2;
                }
                sv[0] = (short)f2bf(v.x); sv[1] = (short)f2bf(v.y);
                sv[2] = (short)f2bf(v.z); sv[3] = (short)f2bf(v.w);
            } else {
                sv[0] = 0; sv[1] = 0; sv[2] = 0; sv[3] = 0;
            }
            unsigned short* dst = arr ? Bs : As;
            *(short4v*)&dst[m * LDM + c4] = sv;
        }
        __syncthreads();
        int mlo = 8 * (lane >> 4);
        int dl = lane & 15;
        bf16x8 af[4], bfv[4];
        #pragma unroll
        for (int tr = 0; tr < 4; ++tr) {
            int col = wr * 64 + tr * 16 + dl;
            #pragma unroll
            for (int u = 0; u < 8; ++u)
                af[tr][u] = (short)As[(mlo + u) * LDM + col];
        }
        #pragma unroll
        for (int tc = 0; tc < 4; ++tc) {
            int col = wc * 64 + tc * 16 + dl;
            #pragma unroll
            for (int u = 0; u < 8; ++u)
                bfv[tc][u] = (short)Bs[(mlo + u) * LDM + col];
        }
        #pragma unroll
        for (int tr = 0; tr < 4; ++tr)
            #pragma unroll
            for (int tc = 0; tc < 4; ++tc)
                acc[tr][tc] = __builtin_amdgcn_mfma_f32_16x16x32_bf16(
                    af[tr], bfv[tc], acc[tr][tc], 0, 0, 0);
        __syncthreads();
    }

    // epilogue (verified in round 5)
    const float* sqb = ws + WS_SQ + b * DIM;
    float sqi[4][4], sqj[4];
    int rbase = ti * 128 + wr * 64;
    int cbase = tj * 128 + wc * 64;
    #pragma unroll
    for (int tr = 0; tr < 4; ++tr)
        #pragma unroll
        for (int rg = 0; rg < 4; ++rg)
            sqi[tr][rg] = sqb[rbase + tr * 16 + (lane >> 4) * 4 + rg];
    #pragma unroll
    for (int tc = 0; tc < 4; ++tc)
        sqj[tc] = sqb[cbase + tc * 16 + (lane & 15)];

    float* adc = out + OUT_ADC + (size_t)b * RTRI;
    float rs[4][4] = {};
    float cs[4] = {0.f, 0.f, 0.f, 0.f};
    #pragma unroll
    for (int tr = 0; tr < 4; ++tr) {
        #pragma unroll
        for (int tc = 0; tc < 4; ++tc) {
            #pragma unroll
            for (int rg = 0; rg < 4; ++rg) {
                int gi = rbase + tr * 16 + (lane >> 4) * 4 + rg;
                int gj = cbase + tc * 16 + (lane & 15);
                float dc = sqi[tr][rg] + sqj[tc] - acc[tr][tc][rg] * (1.0f / 196.0f);
                if (gi == gj) dc = 0.f;
                dc = fmaxf(dc, 0.f) + 1e-5f;
                float val = __expf(0.4f * __logf(dc));
                rs[tr][rg] += val;
                cs[tc] += val;
                if (gj >= gi)
                    adc[gi * (769 - gi) / 2 + (gj - gi)] = val;
            }
        }
    }
    #pragma unroll
    for (int tr = 0; tr < 4; ++tr)
        #pragma unroll
        for (int rg = 0; rg < 4; ++rg) {
            float v = rs[tr][rg];
            v += __shfl_xor(v, 1); v += __shfl_xor(v, 2);
            v += __shfl_xor(v, 4); v += __shfl_xor(v, 8);
            rs[tr][rg] = v;
        }
    if ((lane & 15) == 0) {
        #pragma unroll
        for (int tr = 0; tr < 4; ++tr)
            #pragma unroll
            for (int rg = 0; rg < 4; ++rg)
                atomicAdd(&ws[WS_RSUM + b * DIM + rbase + tr * 16 + (lane >> 4) * 4 + rg],
                          rs[tr][rg]);
    }
    if (ti != tj) {
        #pragma unroll
        for (int tc = 0; tc < 4; ++tc) {
            float v = cs[tc];
            v += __shfl_xor(v, 16); v += __shfl_xor(v, 32);
            cs[tc] = v;
        }
        if (lane < 16) {
            #pragma unroll
            for (int tc = 0; tc < 4; ++tc)
                atomicAdd(&ws[WS_RSUM + b * DIM + cbase + tc * 16 + lane], cs[tc]);
        }
    }
}

// k3: row means + grand mean
__global__ __launch_bounds__(384) void k_rowmean(float* __restrict__ ws) {
    int b = blockIdx.x, i = threadIdx.x;
    float s = ws[WS_RSUM + b * DIM + i];
    ws[WS_RM + b * DIM + i] = s * (1.0f / 384.0f);
    __shared__ float red[6];
    float tsum = wave_reduce(s);
    int lane = i & 63, wv = i >> 6;
    if (!lane) red[wv] = tsum;
    __syncthreads();
    if (i == 0) {
        float tot = red[0]+red[1]+red[2]+red[3]+red[4]+red[5];
        ws[WS_GM + b] = tot * (1.0f / (384.0f * 384.0f));
    }
}

// k4: in-place centering of adc (fp32), row-walk, + qnorm^2 partials
__global__ __launch_bounds__(256) void k_center(float* __restrict__ ws,
                                                float* __restrict__ out) {
    int s = blockIdx.x;       // row class i % 4 (load balance)
    int b = blockIdx.y;
    int tid = threadIdx.x;
    __shared__ float rmL[DIM];
    __shared__ float redL[4];
    const float* rm = ws + WS_RM + b * DIM;
    rmL[tid] = rm[tid];
    if (tid < DIM - 256) rmL[256 + tid] = rm[256 + tid];
    float gm = ws[WS_GM + b];
    __syncthreads();
    float* adc = out + OUT_ADC + (size_t)b * RTRI;
    float acc = 0.f;
    for (int i = s; i < DIM; i += 4) {
        int base = i * (769 - i) / 2;
        int L = DIM - i;
        float rmi = rmL[i] - gm;
        for (int off = tid; off < L; off += 256) {
            float v = adc[base + off];
            float nv = v - rmi - rmL[i + off];
            adc[base + off] = nv;
            acc = fmaf(nv, nv, acc);
        }
    }
    float t = wave_reduce(acc);
    if (!(tid & 63)) redL[tid >> 6] = t;
    __syncthreads();
    if (!tid) ws[WS_QPART + b * 8 + s] = redL[0] + redL[1] + redL[2] + redL[3];
}

// k5: DOTS[r][c] = dot(query r, ctx c) via split-K bf16 MFMA.
// grid (2,2,NS2): 104x104 output quadrant (padded 128x128), 8 waves (2x4).
#define DKD 32              // K per step
#define LDK 40              // LDS stride in bf16 (80 B: 2-way max aliasing)
#define NS2 66
#define CHB 35              // chunks per block: 66*35*32 = 73920
__global__ __launch_bounds__(512) void k_dots(const float* __restrict__ out,
                                              float* __restrict__ ws) {
    int qi = blockIdx.x, qj = blockIdx.y, ns = blockIdx.z;
    int tid = threadIdx.x;
    int lane = tid & 63, w = tid >> 6;
    int wr = w >> 2, wc = w & 3;        // 2x4 waves: 64 rows x 32 cols each
    __shared__ __align__(16) unsigned short As[128 * LDK];
    __shared__ __align__(16) unsigned short Bs[128 * LDK];
    const float* adc = out + OUT_ADC;
    int realA = (qi == 0) ? 104 : 96;
    int realB = (qj == 0) ? 104 : 96;
    const float* qb = adc + (size_t)(NSUP + qi * 104) * RTRI;
    const float* cb = adc + (size_t)(qj * 104) * RTRI;

    f32x4 acc[4][2] = {};
    for (int ck = 0; ck < CHB; ++ck) {
        int k0 = (ns * CHB + ck) * DKD;
        #pragma unroll
        for (int it = 0; it < 4; ++it) {
            int idx = tid + it * 512;
            int arr = idx >> 10;
            int r = (idx >> 3) & 127;
            int kq = (idx & 7) << 2;
            const float* src = arr ? cb : qb;
            int real = arr ? realB : realA;
            float4 v = make_float4(0.f, 0.f, 0.f, 0.f);
            if (r < real) v = *(const float4*)&src[(size_t)r * RTRI + k0 + kq];
            short4v sv;
            sv[0] = (short)f2bf(v.x); sv[1] = (short)f2bf(v.y);
            sv[2] = (short)f2bf(v.z); sv[3] = (short)f2bf(v.w);
            unsigned short* dst = arr ? Bs : As;
            *(short4v*)&dst[r * LDK + kq] = sv;
        }
        __syncthreads();
        int kb = (lane >> 4) * 8;
        bf16x8 af[4], bfv[2];
        #pragma unroll
        for (int tr = 0; tr < 4; ++tr)
            af[tr] = *(const bf16x8*)&As[(wr * 64 + tr * 16 + (lane & 15)) * LDK + kb];
        #pragma unroll
        for (int tc = 0; tc < 2; ++tc)
            bfv[tc] = *(const bf16x8*)&Bs[(wc * 32 + tc * 16 + (lane & 15)) * LDK + kb];
        #pragma unroll
        for (int tr = 0; tr < 4; ++tr)
            #pragma unroll
            for (int tc = 0; tc < 2; ++tc)
                acc[tr][tc] = __builtin_amdgcn_mfma_f32_16x16x32_bf16(
                    af[tr], bfv[tc], acc[tr][tc], 0, 0, 0);
        __syncthreads();
    }
    #pragma unroll
    for (int tr = 0; tr < 4; ++tr)
        #pragma unroll
        for (int tc = 0; tc < 2; ++tc)
            #pragma unroll
            for (int rg = 0; rg < 4; ++rg) {
                int lr = wr * 64 + tr * 16 + (lane >> 4) * 4 + rg;
                int lc = wc * 32 + tc * 16 + (lane & 15);
                if (lr < realA && lc < realB)
                    atomicAdd(&ws[WS_DOTS + (qi * 104 + lr) * 200 + (qj * 104 + lc)],
                              acc[tr][tc][rg]);
            }
}

// k5b: partial within-class ctx pair dots -> PNP[o][15], split-K
__global__ __launch_bounds__(256) void k_pn(const int* __restrict__ labels,
                                            const float* __restrict__ out,
                                            float* __restrict__ ws) {
    int o = blockIdx.x;      // c*8+f
    int sp = blockIdx.y;     // 0..7 K split
    int c = o >> 3, f = o & 7;
    int tid = threadIdx.x;
    __shared__ int rows[5];
    if (tid == 0) {
        int cnt = 0;
        for (int s = 0; s < 25; s++)
            if (labels[s] == c && cnt < 5) rows[cnt++] = s * 8 + f;
    }
    __syncthreads();
    const float* adc = out + OUT_ADC;
    float acc[15] = {};
    int lo = sp * 9240, hi = lo + 9240;
    for (int k = lo + tid; k < hi; k += 256) {
        float v[5];
        #pragma unroll
        for (int a = 0; a < 5; a++) v[a] = adc[(size_t)rows[a] * RTRI + k];
        int idx = 0;
        #pragma unroll
        for (int a = 0; a < 5; a++)
            #pragma unroll
            for (int b2 = a; b2 < 5; b2++) {
                acc[idx] = fmaf(v[a], v[b2], acc[idx]);
                idx++;
            }
    }
    __shared__ float red[15];
    if (tid < 15) red[tid] = 0.f;
    __syncthreads();
    #pragma unroll
    for (int i = 0; i < 15; i++) {
        float t = wave_reduce(acc[i]);
        if (!(tid & 63)) atomicAdd(&red[i], t);
    }
    __syncthreads();
    if (tid < 15) atomicAdd(&ws[WS_PNP + o * 16 + tid], red[tid]);
}

// k6: qn + pn finalize + ad from DOTS/PNP/QPART
__global__ __launch_bounds__(256) void k_post(const int* __restrict__ labels,
                                              float* __restrict__ ws) {
    __shared__ int mem[5][5];
    int tid = threadIdx.x;
    if (tid == 0) {
        int cnt[5] = {0,0,0,0,0};
        for (int s = 0; s < 25; s++) { int c = labels[s]; if (cnt[c] < 5) mem[c][cnt[c]++] = s; }
    }
    __syncthreads();
    for (int r = tid; r < 200; r += 256) {
        float ssum = 0.f;
        #pragma unroll
        for (int k = 0; k < 8; k++) ssum += ws[WS_QPART + (200 + r) * 8 + k];
        ws[WS_QN + r] = fmaxf(sqrtf(fmaxf(ssum, 0.f)), 1e-8f);
    }
    if (tid < 40) {
        float tot = 0.f;
        int idx = 0;
        #pragma unroll
        for (int a = 0; a < 5; a++)
            #pragma unroll
            for (int b2 = a; b2 < 5; b2++) {
                tot += ((a == b2) ? 1.f : 2.f) * ws[WS_PNP + tid * 16 + idx];
                idx++;
            }
        ws[WS_PN + tid] = fmaxf(sqrtf(fmaxf(tot, 0.f)) * 0.2f, 1e-8f);
    }
    __syncthreads();
    for (int idx = tid; idx < 8000; idx += 256) {
        int r = idx / 40, o = idx % 40;
        int c = o >> 3, f = o & 7;
        float s = 0.f;
        #pragma unroll
        for (int a = 0; a < 5; a++)
            s += ws[WS_DOTS + r * 200 + mem[c][a] * 8 + f];
        ws[WS_AD + idx] = s * 0.2f;
    }
}

// k7: proto[q] = mean_f(query cls) + mean_all(support cls)
__global__ __launch_bounds__(384) void k_proto(const float* __restrict__ lsn,
                                               float* __restrict__ ws) {
    int tid = threadIdx.x;
    float tsv = 0.f;
    for (int r = 0; r < 200; r++) tsv += lsn[(size_t)r * 197 * DIM + tid];
    tsv *= (1.0f / 200.0f);
    for (int q = 0; q < 25; q++) {
        float s = 0.f;
        #pragma unroll
        for (int f = 0; f < 8; f++) s += lsn[(size_t)(200 + q * 8 + f) * 197 * DIM + tid];
        ws[WS_PROTO + q * DIM + tid] = s * (1.0f / 8.0f) + tsv;
    }
}

// k8: tsm[q][g] = proto[q] . gen_weight[g]
__global__ __launch_bounds__(64) void k_tsm(const float* __restrict__ gw,
                                            float* __restrict__ ws) {
    int q = blockIdx.x, g = threadIdx.x;
    const float* pr = ws + WS_PROTO + q * DIM;
    const float* gr = gw + g * DIM;
    float s = 0.f;
    for (int d = 0; d < DIM; d++) s = fmaf(pr[d], gr[d], s);
    ws[WS_TSM + q * 64 + g] = s;
}

// k9: final score
__global__ __launch_bounds__(128) void k_score(const float* __restrict__ ws,
                                               float* __restrict__ out) {
    int t = threadIdx.x;
    if (t >= 125) return;
    int q = t / 5, wway = t % 5;
    float s = 0.f;
    for (int f = 0; f < 8; f++) {
        float qn = ws[WS_QN + q * 8 + f];
        for (int g = 0; g < 8; g++) {
            float ad = ws[WS_AD + (q * 8 + f) * 40 + wway * 8 + g];
            float pnv = ws[WS_PN + wway * 8 + g];
            s += (ad / (qn * pnv)) * ws[WS_TSM + q * 64 + f * 8 + g];
        }
    }
    out[OUT_SCORE + t] = s;
}

extern "C" void kernel_launch(void* const* d_in, const int* in_sizes, int n_in,
                              void* d_out, int out_size, void* d_ws, size_t ws_size,
                              hipStream_t stream) {
    const float* lsn = (const float*)d_in[0];
    const float* gw = (const float*)d_in[1];
    const int* labels = (const int*)d_in[2];
    float* ws = (float*)d_ws;
    float* out = (float*)d_out;

    {
        int n = (WS_AD - WS_RSUM);   // RSUM, RM, GM, QPART, DOTS, PNP
        k_zero<<<dim3((n + 255) / 256), dim3(256), 0, stream>>>(ws + WS_RSUM, n);
    }
    k_prep<<<dim3(BATCH), dim3(384), 0, stream>>>(lsn, ws, out);
    k_gram<<<dim3(6, BATCH), dim3(256), 0, stream>>>(lsn, ws, out);
    k_rowmean<<<dim3(BATCH), dim3(384), 0, stream>>>(ws);
    k_center<<<dim3(4, BATCH), dim3(256), 0, stream>>>(ws, out);
    k_dots<<<dim3(2, 2, NS2), dim3(512), 0, stream>>>(out, ws);
    k_pn<<<dim3(40, 8), dim3(256), 0, stream>>>(labels, out, ws);
    k_post<<<1, dim3(256), 0, stream>>>(labels, ws);
    k_proto<<<1, dim3(384), 0, stream>>>(lsn, ws);
    k_tsm<<<dim3(25), dim3(64), 0, stream>>>(gw, ws);
    k_score<<<1, dim3(128), 0, stream>>>(ws, out);
}